// Round 9
// baseline (113.327 us; speedup 1.0000x reference)
//
#include <hip/hip_runtime.h>

// TriangleAttentionStartingNode — MI355X gfx950. f32 global I/O, bf16 MFMA compute.
//
// R13: LDS-pipe + ILP round. R12 confirmed the issue-stream-bound model
// (libm fixup removal: 51.5 -> 42.5us, VALUBusy 55->40 at shorter dur).
// Remaining budget at 102K cycles: attention ds_read_b64 = 512/thread
// (p2-outer reloads K/V frags per q-tile) ~= 30K cycles of shared LDS pipe.
// Change (bit-identical math): attention loop nesting swapped to kb-outer /
// p2-inner KEEPING R8's conflict-free uint2 layouts — this is the good half
// of R10 without the b128 re-layout that quadrupled bank conflicts:
//   - K/V fragment loads halve (8 ds_read_b64/kb serve both q-tiles);
//   - two independent S->exp2->pack->PV chains per kb (2x ILP in the
//     serial-chain region);
//   - K/V frags live across p2: +16 VGPR (~104 -> ~115, under the 128 step).
//
// Kept from R12: raw HW transcendentals (__builtin_amdgcn_exp2f / rcpf /
// rsqf — no libm denormal fixup); grid (2,256), 256 thr; split-K staging
// (two 128-key halves/head, LDS 38.1 KB); plain __launch_bounds__(256)
// (2nd arg spills ~50 regs, R5/R6); v_perm round-half-up bf16 packing;
// softmax scale*log2e folded into Q; Wb unused (softmax shift invariance);
// tree-reduced l.

typedef unsigned short u16;
typedef unsigned int   u32;
typedef __bf16 bf16x8 __attribute__((ext_vector_type(8)));
typedef float  f32x4  __attribute__((ext_vector_type(4)));

union U8 { bf16x8 b; u32 u[4]; };

// round-half-up f32->bf16 pair pack: 2 adds + 1 v_perm
__device__ __forceinline__ u32 pk(float a, float b) {
  const u32 au = __float_as_uint(a) + 0x8000u;
  const u32 bu = __float_as_uint(b) + 0x8000u;
  return __builtin_amdgcn_perm(bu, au, 0x07060302u);  // {b.hi16, a.hi16}
}
__device__ __forceinline__ f32x4 mfma16(bf16x8 a, bf16x8 b, f32x4 c) {
  return __builtin_amdgcn_mfma_f32_16x16x32_bf16(a, b, c, 0, 0, 0);
}
// raw v_exp_f32 (no libm denormal fixup)
__device__ __forceinline__ float ex2(float x) { return __builtin_amdgcn_exp2f(x); }
// sigmoid via v_exp + v_rcp (1 ulp)
__device__ __forceinline__ float sigm(float x) {
  return __builtin_amdgcn_rcpf(1.f + __builtin_amdgcn_exp2f(-1.44269504089f * x));
}

#define LDZ 40    // 80 B rows (16B-aligned uint4 reads)
#define LDK 36    // 72 B rows
#define LDV 132   // 264 B rows

__global__ __launch_bounds__(256) void tri_attn_fused(
    const float* __restrict__ z,  const float* __restrict__ ln_g, const float* __restrict__ ln_b,
    const float* __restrict__ Wq, const float* __restrict__ Wk,   const float* __restrict__ Wv,
    const float* __restrict__ Wg, const float* __restrict__ bg,
    const float* __restrict__ Wo, const float* __restrict__ bo,   float* __restrict__ out)
{
  __shared__ u16 sZ [256][LDZ];   // zn[pos][ch]   bf16               20480 B
  __shared__ u16 sK [128][LDK];   // K[key%128][ch] bf16 (per half)    9216 B
  __shared__ u16 sVt[32][LDV];    // V^T[ch][key%128] bf16 (per half)  8448 B

  const int qhalf = blockIdx.x;
  const int i     = blockIdx.y;
  const int tid   = threadIdx.x;
  const int wave  = tid >> 6, lane = tid & 63, quad = lane >> 4, col = lane & 15;
  const f32x4 z4  = {0.f, 0.f, 0.f, 0.f};

  // ---------------- phase 0: LayerNorm (one thread per position) ----------------
  {
    const float* zr = z + (((i << 8) + tid) << 5);
    float x[32];
#pragma unroll
    for (int e = 0; e < 8; e++) {
      const float4 v = *(const float4*)(zr + e*4);
      x[4*e] = v.x; x[4*e+1] = v.y; x[4*e+2] = v.z; x[4*e+3] = v.w;
    }
    float mu = 0.f;
#pragma unroll
    for (int c = 0; c < 32; c++) mu += x[c];
    mu *= (1.f / 32.f);
    float s2 = 0.f;
#pragma unroll
    for (int c = 0; c < 32; c++) { float d = x[c] - mu; s2 += d * d; }
    const float rstd = __builtin_amdgcn_rsqf(s2 * (1.f / 32.f) + 1e-5f);
    u32* dst = (u32*)&sZ[tid][0];
#pragma unroll
    for (int e = 0; e < 16; e++) {
      const float za = (x[2*e]   - mu) * rstd * ln_g[2*e]   + ln_b[2*e];
      const float zb = (x[2*e+1] - mu) * rstd * ln_g[2*e+1] + ln_b[2*e+1];
      dst[e] = pk(za, zb);
    }
  }
  __syncthreads();

  f32x4 acc[2][2] = {{z4, z4}, {z4, z4}};   // fp32 out accumulators (across heads)
  const float k2e = 0.17677669529663687f * 1.44269504089f;   // (1/sqrt32)*log2(e)

  for (int h = 0; h < 4; ++h) {
    // weight fragments (f32 -> bf16 pack), loaded once per head (L1/L2-hot)
    auto ldw = [&](const float* W, int cb) -> U8 {
      const float* p = W + h*1024 + (cb*16 + col)*32 + quad*8;
      const float4 a = *(const float4*)(p);
      const float4 b = *(const float4*)(p + 4);
      U8 t;
      t.u[0] = pk(a.x, a.y); t.u[1] = pk(a.z, a.w);
      t.u[2] = pk(b.x, b.y); t.u[3] = pk(b.z, b.w);
      return t;
    };

    // -------- Q/G pre-phase: this block's 128 queries (2 tiles/wave) --------
    U8    QB[2];        // Q (pre-scaled) permuted-k B-frags
    float G[2][8];      // gates, O^T C-layout
    {
      const U8 WqF0 = ldw(Wq,0), WqF1 = ldw(Wq,1);
      const U8 WgF0 = ldw(Wg,0), WgF1 = ldw(Wg,1);
      float bgl[8];
#pragma unroll
      for (int r = 0; r < 4; r++) {
        bgl[r]     = bg[h*32 + quad*4 + r];
        bgl[4 + r] = bg[h*32 + 16 + quad*4 + r];
      }
#pragma unroll
      for (int p2 = 0; p2 < 2; p2++) {
        const int row = qhalf*128 + (p2*4 + wave)*16 + col;
        U8 ZA;
        {
          const uint4 v = *(const uint4*)&sZ[row][quad*8];
          ZA.u[0] = v.x; ZA.u[1] = v.y; ZA.u[2] = v.z; ZA.u[3] = v.w;
        }
        const f32x4 q0 = mfma16(WqF0.b, ZA.b, z4);
        const f32x4 q1 = mfma16(WqF1.b, ZA.b, z4);
        const f32x4 g0 = mfma16(WgF0.b, ZA.b, z4);
        const f32x4 g1 = mfma16(WgF1.b, ZA.b, z4);
        QB[p2].u[0] = pk(q0[0]*k2e, q0[1]*k2e); QB[p2].u[1] = pk(q0[2]*k2e, q0[3]*k2e);
        QB[p2].u[2] = pk(q1[0]*k2e, q1[1]*k2e); QB[p2].u[3] = pk(q1[2]*k2e, q1[3]*k2e);
#pragma unroll
        for (int r = 0; r < 4; r++) {
          G[p2][r]     = sigm(g0[r] + bgl[r]);
          G[p2][4 + r] = sigm(g1[r] + bgl[4 + r]);
        }
      }
    }

    const U8 WkF0 = ldw(Wk,0), WkF1 = ldw(Wk,1);
    const U8 WvF0 = ldw(Wv,0), WvF1 = ldw(Wv,1);

    float l[2]     = {0.f, 0.f};
    f32x4 O[2][2]  = {{z4, z4}, {z4, z4}};   // O^T per p2: ch=quad*4+r (+16), q=col

    // -------- two 128-key halves: project -> sync -> attend -> sync --------
#pragma unroll
    for (int m = 0; m < 2; m++) {
      // projection of keys m*128 .. m*128+127 (4 waves x 2 tiles of 16)
#pragma unroll
      for (int pp = 0; pp < 2; pp++) {
        const int lbase = (pp*4 + wave) * 16;        // local key base (0..112)
        const int grow  = m*128 + lbase + col;       // global position
        U8 ZA;
        {
          const uint4 v = *(const uint4*)&sZ[grow][quad*8];
          ZA.u[0] = v.x; ZA.u[1] = v.y; ZA.u[2] = v.z; ZA.u[3] = v.w;
        }
        // K^T (C-layout: ch=quad*4+reg, key=col), V (key=quad*4+reg, ch=col)
        const f32x4 k0 = mfma16(WkF0.b, ZA.b, z4);
        const f32x4 k1 = mfma16(WkF1.b, ZA.b, z4);
        const f32x4 v0 = mfma16(ZA.b, WvF0.b, z4);
        const f32x4 v1 = mfma16(ZA.b, WvF1.b, z4);
        *(uint2*)&sK[lbase + col][quad*4]        = make_uint2(pk(k0[0],k0[1]), pk(k0[2],k0[3]));
        *(uint2*)&sK[lbase + col][16 + quad*4]   = make_uint2(pk(k1[0],k1[1]), pk(k1[2],k1[3]));
        *(uint2*)&sVt[col][lbase + quad*4]       = make_uint2(pk(v0[0],v0[1]), pk(v0[2],v0[3]));
        *(uint2*)&sVt[16 + col][lbase + quad*4]  = make_uint2(pk(v1[0],v1[1]), pk(v1[2],v1[3]));
      }
      __syncthreads();

      // ---- attention: kb OUTER (K/V frags shared by both q-tiles), p2 inner ----
#pragma unroll
      for (int kb = 0; kb < 128; kb += 32) {
        U8 KF0, KF1, VF0, VF1;
        {
          const uint2 a = *(const uint2*)&sK[kb + col][quad*4];
          const uint2 b = *(const uint2*)&sK[kb + col][16 + quad*4];
          KF0.u[0] = a.x; KF0.u[1] = a.y; KF0.u[2] = b.x; KF0.u[3] = b.y;
          const uint2 c = *(const uint2*)&sK[kb + 16 + col][quad*4];
          const uint2 d = *(const uint2*)&sK[kb + 16 + col][16 + quad*4];
          KF1.u[0] = c.x; KF1.u[1] = c.y; KF1.u[2] = d.x; KF1.u[3] = d.y;
          const uint2 e = *(const uint2*)&sVt[col][kb + quad*4];
          const uint2 f = *(const uint2*)&sVt[col][kb + 16 + quad*4];
          VF0.u[0] = e.x; VF0.u[1] = e.y; VF0.u[2] = f.x; VF0.u[3] = f.y;
          const uint2 g = *(const uint2*)&sVt[16 + col][kb + quad*4];
          const uint2 k = *(const uint2*)&sVt[16 + col][kb + 16 + quad*4];
          VF1.u[0] = g.x; VF1.u[1] = g.y; VF1.u[2] = k.x; VF1.u[3] = k.y;
        }
#pragma unroll
        for (int p2 = 0; p2 < 2; p2++) {
          const f32x4 S0 = mfma16(KF0.b, QB[p2].b, z4);   // keys kb+quad*4+r
          const f32x4 S1 = mfma16(KF1.b, QB[p2].b, z4);   // keys kb+16+quad*4+r
          float ps[8];
#pragma unroll
          for (int r = 0; r < 4; r++) {
            ps[r]     = ex2(S0[r]);     // scale pre-folded into Q; raw v_exp_f32
            ps[4 + r] = ex2(S1[r]);
          }
          l[p2] += ((ps[0]+ps[1]) + (ps[2]+ps[3])) + ((ps[4]+ps[5]) + (ps[6]+ps[7]));
          U8 PB;
          PB.u[0] = pk(ps[0],ps[1]); PB.u[1] = pk(ps[2],ps[3]);
          PB.u[2] = pk(ps[4],ps[5]); PB.u[3] = pk(ps[6],ps[7]);
          O[p2][0] = mfma16(VF0.b, PB.b, O[p2][0]);
          O[p2][1] = mfma16(VF1.b, PB.b, O[p2][1]);
        }
      }
      __syncthreads();   // protect sK/sVt before the next half / head overwrites
    }

    // -------- epilogue: normalize, gate, fused out-projection --------
    U8 WoA0, WoA1;   // Wo A-frags with matching k-permutation (qt-invariant)
    {
      const float4 a = *(const float4*)(Wo + col*128 + h*32 + quad*4);
      const float4 b = *(const float4*)(Wo + col*128 + h*32 + 16 + quad*4);
      WoA0.u[0] = pk(a.x,a.y); WoA0.u[1] = pk(a.z,a.w);
      WoA0.u[2] = pk(b.x,b.y); WoA0.u[3] = pk(b.z,b.w);
      const float4 c = *(const float4*)(Wo + (16 + col)*128 + h*32 + quad*4);
      const float4 d = *(const float4*)(Wo + (16 + col)*128 + h*32 + 16 + quad*4);
      WoA1.u[0] = pk(c.x,c.y); WoA1.u[1] = pk(c.z,c.w);
      WoA1.u[2] = pk(d.x,d.y); WoA1.u[3] = pk(d.z,d.w);
    }
#pragma unroll
    for (int p2 = 0; p2 < 2; p2++) {
      float lv = l[p2];
      lv += __shfl_xor(lv, 16);   // reduce over quads (keys spread reg-dim x quad)
      lv += __shfl_xor(lv, 32);
      const float inv = __builtin_amdgcn_rcpf(lv);   // 1 ulp, values O(100)
      float og[8];
#pragma unroll
      for (int r = 0; r < 4; r++) {
        og[r]     = O[p2][0][r] * inv * G[p2][r];
        og[4 + r] = O[p2][1][r] * inv * G[p2][4 + r];
      }
      U8 OB;   // gated O^T as permuted-k B-frag (k-permutation matches WoA)
      OB.u[0] = pk(og[0],og[1]); OB.u[1] = pk(og[2],og[3]);
      OB.u[2] = pk(og[4],og[5]); OB.u[3] = pk(og[6],og[7]);
      acc[p2][0] = mfma16(WoA0.b, OB.b, acc[p2][0]);   // couts 0..15
      acc[p2][1] = mfma16(WoA1.b, OB.b, acc[p2][1]);   // couts 16..31
    }
  }

  // ---------------- epilogue: + bo, float4 stores ----------------
  float bo0[4], bo1[4];
#pragma unroll
  for (int r = 0; r < 4; r++) {
    bo0[r] = bo[quad*4 + r];
    bo1[r] = bo[16 + quad*4 + r];
  }
#pragma unroll
  for (int p2 = 0; p2 < 2; p2++) {
    const int pos = (i << 8) + qhalf*128 + (p2*4 + wave)*16 + col;
    float* op = out + pos*32;
    *(float4*)(op + quad*4)      = make_float4(acc[p2][0][0] + bo0[0], acc[p2][0][1] + bo0[1],
                                               acc[p2][0][2] + bo0[2], acc[p2][0][3] + bo0[3]);
    *(float4*)(op + 16 + quad*4) = make_float4(acc[p2][1][0] + bo1[0], acc[p2][1][1] + bo1[1],
                                               acc[p2][1][2] + bo1[2], acc[p2][1][3] + bo1[3]);
  }
}

extern "C" void kernel_launch(void* const* d_in, const int* in_sizes, int n_in,
                              void* d_out, int out_size, void* d_ws, size_t ws_size,
                              hipStream_t stream)
{
  const float* z    = (const float*)d_in[0];
  const float* ln_g = (const float*)d_in[1];
  const float* ln_b = (const float*)d_in[2];
  const float* Wq   = (const float*)d_in[3];
  const float* Wk   = (const float*)d_in[4];
  const float* Wv   = (const float*)d_in[5];
  // d_in[6] = Wb: softmax shift invariance -> exactly cancels, unused.
  const float* Wg   = (const float*)d_in[7];
  const float* bg   = (const float*)d_in[8];
  const float* Wo   = (const float*)d_in[9];
  const float* bo   = (const float*)d_in[10];

  tri_attn_fused<<<dim3(2, 256), 256, 0, stream>>>(z, ln_g, ln_b, Wq, Wk, Wv, Wg, bg, Wo, bo,
                                                   (float*)d_out);
}

// Round 10
// 112.288 us; speedup vs baseline: 1.0093x; 1.0093x over previous
//
#include <hip/hip_runtime.h>

// TriangleAttentionStartingNode — MI355X gfx950. f32 global I/O, bf16 MFMA compute.
//
// R14: phase-overlap round. Base = R12 (42.5us best; R13's kb-outer nesting
// was -4%, reverted; its real finding: bank conflicts [229K, unchanged by
// halving attn reads] live in the proj/LN path and are negligible, LDS pipe
// NOT critical). Remaining structural cost: 17 barriers/block at ~1.5
// resident blocks/CU, each phase internally serial. Change: double-buffered
// sK/sVt (LDS 38.4 -> 55.8 KB, still 2 blk/CU) + software-pipelined
// schedule: {proj(next half) || attend(current half)} between barriers,
// pipelined across heads (stage B projects head h+1's first half during
// head h's second attend). Every inter-barrier region = serial attention
// chain + independent projection MFMA/pack for the compiler to interleave
// (ILP, where R9 proved TLP can't reach). Barriers 17 -> 10. Math
// bit-identical: same fragments, same ascending-kb accumulation.
//
// Kept from R12: raw HW transcendentals (exp2f/rcpf/rsqf builtins — no libm
// denormal fixup; that was 51.5->42.5); grid (2,256), 256 thr; plain
// __launch_bounds__(256) (2nd arg spills ~50 regs, R5/R6); v_perm
// round-half-up bf16 packing; softmax scale*log2e folded into Q; Wb unused
// (softmax shift invariance); tree-reduced l.

typedef unsigned short u16;
typedef unsigned int   u32;
typedef __bf16 bf16x8 __attribute__((ext_vector_type(8)));
typedef float  f32x4  __attribute__((ext_vector_type(4)));

union U8 { bf16x8 b; u32 u[4]; };

// round-half-up f32->bf16 pair pack: 2 adds + 1 v_perm
__device__ __forceinline__ u32 pk(float a, float b) {
  const u32 au = __float_as_uint(a) + 0x8000u;
  const u32 bu = __float_as_uint(b) + 0x8000u;
  return __builtin_amdgcn_perm(bu, au, 0x07060302u);  // {b.hi16, a.hi16}
}
__device__ __forceinline__ f32x4 mfma16(bf16x8 a, bf16x8 b, f32x4 c) {
  return __builtin_amdgcn_mfma_f32_16x16x32_bf16(a, b, c, 0, 0, 0);
}
// raw v_exp_f32 (no libm denormal fixup)
__device__ __forceinline__ float ex2(float x) { return __builtin_amdgcn_exp2f(x); }
// sigmoid via v_exp + v_rcp (1 ulp)
__device__ __forceinline__ float sigm(float x) {
  return __builtin_amdgcn_rcpf(1.f + __builtin_amdgcn_exp2f(-1.44269504089f * x));
}

#define LDZ 40    // 80 B rows (16B-aligned uint4 reads)
#define LDK 36    // 72 B rows
#define LDV 132   // 264 B rows

__global__ __launch_bounds__(256) void tri_attn_fused(
    const float* __restrict__ z,  const float* __restrict__ ln_g, const float* __restrict__ ln_b,
    const float* __restrict__ Wq, const float* __restrict__ Wk,   const float* __restrict__ Wv,
    const float* __restrict__ Wg, const float* __restrict__ bg,
    const float* __restrict__ Wo, const float* __restrict__ bo,   float* __restrict__ out)
{
  __shared__ u16 sZ [256][LDZ];       // zn[pos][ch] bf16                  20480 B
  __shared__ u16 sK [2][128][LDK];    // K[key%128][ch]  (double-buffered) 18432 B
  __shared__ u16 sVt[2][32][LDV];     // V^T[ch][key%128](double-buffered) 16896 B

  const int qhalf = blockIdx.x;
  const int i     = blockIdx.y;
  const int tid   = threadIdx.x;
  const int wave  = tid >> 6, lane = tid & 63, quad = lane >> 4, col = lane & 15;
  const f32x4 z4  = {0.f, 0.f, 0.f, 0.f};

  // ---------------- phase 0: LayerNorm (one thread per position) ----------------
  {
    const float* zr = z + (((i << 8) + tid) << 5);
    float x[32];
#pragma unroll
    for (int e = 0; e < 8; e++) {
      const float4 v = *(const float4*)(zr + e*4);
      x[4*e] = v.x; x[4*e+1] = v.y; x[4*e+2] = v.z; x[4*e+3] = v.w;
    }
    float mu = 0.f;
#pragma unroll
    for (int c = 0; c < 32; c++) mu += x[c];
    mu *= (1.f / 32.f);
    float s2 = 0.f;
#pragma unroll
    for (int c = 0; c < 32; c++) { float d = x[c] - mu; s2 += d * d; }
    const float rstd = __builtin_amdgcn_rsqf(s2 * (1.f / 32.f) + 1e-5f);
    u32* dst = (u32*)&sZ[tid][0];
#pragma unroll
    for (int e = 0; e < 16; e++) {
      const float za = (x[2*e]   - mu) * rstd * ln_g[2*e]   + ln_b[2*e];
      const float zb = (x[2*e+1] - mu) * rstd * ln_g[2*e+1] + ln_b[2*e+1];
      dst[e] = pk(za, zb);
    }
  }
  __syncthreads();

  f32x4 acc[2][2] = {{z4, z4}, {z4, z4}};   // fp32 out accumulators (across heads)
  const float k2e = 0.17677669529663687f * 1.44269504089f;   // (1/sqrt32)*log2(e)

  // weight fragments (f32 -> bf16 pack), L1/L2-hot
  auto ldw = [&](const float* W, int h, int cb) -> U8 {
    const float* p = W + h*1024 + (cb*16 + col)*32 + quad*8;
    const float4 a = *(const float4*)(p);
    const float4 b = *(const float4*)(p + 4);
    U8 t;
    t.u[0] = pk(a.x, a.y); t.u[1] = pk(a.z, a.w);
    t.u[2] = pk(b.x, b.y); t.u[3] = pk(b.z, b.w);
    return t;
  };

  U8    QB[2];       // Q (pre-scaled) permuted-k B-frags, per head
  float G[2][8];     // gates, O^T C-layout, per head

  // Q/G for head h: this block's 128 queries (2 tiles/wave); reads sZ only
  auto qg = [&](int h) {
    const U8 WqF0 = ldw(Wq,h,0), WqF1 = ldw(Wq,h,1);
    const U8 WgF0 = ldw(Wg,h,0), WgF1 = ldw(Wg,h,1);
    float bgl[8];
#pragma unroll
    for (int r = 0; r < 4; r++) {
      bgl[r]     = bg[h*32 + quad*4 + r];
      bgl[4 + r] = bg[h*32 + 16 + quad*4 + r];
    }
#pragma unroll
    for (int p2 = 0; p2 < 2; p2++) {
      const int row = qhalf*128 + (p2*4 + wave)*16 + col;
      U8 ZA;
      {
        const uint4 v = *(const uint4*)&sZ[row][quad*8];
        ZA.u[0] = v.x; ZA.u[1] = v.y; ZA.u[2] = v.z; ZA.u[3] = v.w;
      }
      const f32x4 q0 = mfma16(WqF0.b, ZA.b, z4);
      const f32x4 q1 = mfma16(WqF1.b, ZA.b, z4);
      const f32x4 g0 = mfma16(WgF0.b, ZA.b, z4);
      const f32x4 g1 = mfma16(WgF1.b, ZA.b, z4);
      QB[p2].u[0] = pk(q0[0]*k2e, q0[1]*k2e); QB[p2].u[1] = pk(q0[2]*k2e, q0[3]*k2e);
      QB[p2].u[2] = pk(q1[0]*k2e, q1[1]*k2e); QB[p2].u[3] = pk(q1[2]*k2e, q1[3]*k2e);
#pragma unroll
      for (int r = 0; r < 4; r++) {
        G[p2][r]     = sigm(g0[r] + bgl[r]);
        G[p2][4 + r] = sigm(g1[r] + bgl[4 + r]);
      }
    }
  };

  // project keys m*128..m*128+127 into buffer buf (reads sZ only)
  auto proj = [&](const U8& K0w, const U8& K1w, const U8& V0w, const U8& V1w,
                  int m, int buf) {
#pragma unroll
    for (int pp = 0; pp < 2; pp++) {
      const int lbase = (pp*4 + wave) * 16;        // local key base (0..112)
      const int grow  = m*128 + lbase + col;       // global position
      U8 ZA;
      {
        const uint4 v = *(const uint4*)&sZ[grow][quad*8];
        ZA.u[0] = v.x; ZA.u[1] = v.y; ZA.u[2] = v.z; ZA.u[3] = v.w;
      }
      // K^T (C-layout: ch=quad*4+reg, key=col), V (key=quad*4+reg, ch=col)
      const f32x4 k0 = mfma16(K0w.b, ZA.b, z4);
      const f32x4 k1 = mfma16(K1w.b, ZA.b, z4);
      const f32x4 v0 = mfma16(ZA.b, V0w.b, z4);
      const f32x4 v1 = mfma16(ZA.b, V1w.b, z4);
      *(uint2*)&sK[buf][lbase + col][quad*4]        = make_uint2(pk(k0[0],k0[1]), pk(k0[2],k0[3]));
      *(uint2*)&sK[buf][lbase + col][16 + quad*4]   = make_uint2(pk(k1[0],k1[1]), pk(k1[2],k1[3]));
      *(uint2*)&sVt[buf][col][lbase + quad*4]       = make_uint2(pk(v0[0],v0[1]), pk(v0[2],v0[3]));
      *(uint2*)&sVt[buf][16 + col][lbase + quad*4]  = make_uint2(pk(v1[0],v1[1]), pk(v1[2],v1[3]));
    }
  };

  // -------- prologue: head 0 Q/G + first half projection --------
  U8 KC0 = ldw(Wk,0,0), KC1 = ldw(Wk,0,1);   // current head's K/V weight frags
  U8 VC0 = ldw(Wv,0,0), VC1 = ldw(Wv,0,1);
  qg(0);
  proj(KC0, KC1, VC0, VC1, 0, 0);
  __syncthreads();

  for (int h = 0; h < 4; ++h) {
    float l[2]    = {0.f, 0.f};
    f32x4 O[2][2] = {{z4, z4}, {z4, z4}};   // O^T per p2: ch=quad*4+r (+16), q=col

    // attention over one buffered half (R12 structure: p2 outer, kb inner)
    auto attend = [&](int buf) {
#pragma unroll
      for (int p2 = 0; p2 < 2; p2++) {
#pragma unroll
        for (int kb = 0; kb < 128; kb += 32) {
          U8 KF0, KF1;
          {
            const uint2 a = *(const uint2*)&sK[buf][kb + col][quad*4];
            const uint2 b = *(const uint2*)&sK[buf][kb + col][16 + quad*4];
            KF0.u[0] = a.x; KF0.u[1] = a.y; KF0.u[2] = b.x; KF0.u[3] = b.y;
            const uint2 c = *(const uint2*)&sK[buf][kb + 16 + col][quad*4];
            const uint2 d = *(const uint2*)&sK[buf][kb + 16 + col][16 + quad*4];
            KF1.u[0] = c.x; KF1.u[1] = c.y; KF1.u[2] = d.x; KF1.u[3] = d.y;
          }
          const f32x4 S0 = mfma16(KF0.b, QB[p2].b, z4);   // keys kb+quad*4+r
          const f32x4 S1 = mfma16(KF1.b, QB[p2].b, z4);   // keys kb+16+quad*4+r
          float ps[8];
#pragma unroll
          for (int r = 0; r < 4; r++) {
            ps[r]     = ex2(S0[r]);     // scale pre-folded into Q; raw v_exp_f32
            ps[4 + r] = ex2(S1[r]);
          }
          l[p2] += ((ps[0]+ps[1]) + (ps[2]+ps[3])) + ((ps[4]+ps[5]) + (ps[6]+ps[7]));
          U8 PB;
          PB.u[0] = pk(ps[0],ps[1]); PB.u[1] = pk(ps[2],ps[3]);
          PB.u[2] = pk(ps[4],ps[5]); PB.u[3] = pk(ps[6],ps[7]);
          U8 VF0, VF1;
          {
            const uint2 a = *(const uint2*)&sVt[buf][col][kb + quad*4];
            const uint2 b = *(const uint2*)&sVt[buf][col][kb + 16 + quad*4];
            VF0.u[0] = a.x; VF0.u[1] = a.y; VF0.u[2] = b.x; VF0.u[3] = b.y;
            const uint2 c = *(const uint2*)&sVt[buf][16 + col][kb + quad*4];
            const uint2 d = *(const uint2*)&sVt[buf][16 + col][kb + 16 + quad*4];
            VF1.u[0] = c.x; VF1.u[1] = c.y; VF1.u[2] = d.x; VF1.u[3] = d.y;
          }
          O[p2][0] = mfma16(VF0.b, PB.b, O[p2][0]);
          O[p2][1] = mfma16(VF1.b, PB.b, O[p2][1]);
        }
      }
    };

    // ---- stage A: proj(head h, half 1 -> buf1) overlapped with attend(buf0) ----
    proj(KC0, KC1, VC0, VC1, 1, 1);
    attend(0);
    __syncthreads();   // buf1 ready; buf0 free

    // ---- stage B: proj(head h+1, half 0 -> buf0) overlapped with attend(buf1) ----
    if (h < 3) {
      const U8 KN0 = ldw(Wk,h+1,0), KN1 = ldw(Wk,h+1,1);
      const U8 VN0 = ldw(Wv,h+1,0), VN1 = ldw(Wv,h+1,1);
      proj(KN0, KN1, VN0, VN1, 0, 0);
      KC0 = KN0; KC1 = KN1; VC0 = VN0; VC1 = VN1;
    }
    attend(1);
    __syncthreads();   // buf0 ready for next head; buf1 free

    // -------- epilogue: normalize, gate, fused out-projection (regs only) --------
    U8 WoA0, WoA1;   // Wo A-frags with matching k-permutation (qt-invariant)
    {
      const float4 a = *(const float4*)(Wo + col*128 + h*32 + quad*4);
      const float4 b = *(const float4*)(Wo + col*128 + h*32 + 16 + quad*4);
      WoA0.u[0] = pk(a.x,a.y); WoA0.u[1] = pk(a.z,a.w);
      WoA0.u[2] = pk(b.x,b.y); WoA0.u[3] = pk(b.z,b.w);
      const float4 c = *(const float4*)(Wo + (16 + col)*128 + h*32 + quad*4);
      const float4 d = *(const float4*)(Wo + (16 + col)*128 + h*32 + 16 + quad*4);
      WoA1.u[0] = pk(c.x,c.y); WoA1.u[1] = pk(c.z,c.w);
      WoA1.u[2] = pk(d.x,d.y); WoA1.u[3] = pk(d.z,d.w);
    }
#pragma unroll
    for (int p2 = 0; p2 < 2; p2++) {
      float lv = l[p2];
      lv += __shfl_xor(lv, 16);   // reduce over quads (keys spread reg-dim x quad)
      lv += __shfl_xor(lv, 32);
      const float inv = __builtin_amdgcn_rcpf(lv);   // 1 ulp, values O(100)
      float og[8];
#pragma unroll
      for (int r = 0; r < 4; r++) {
        og[r]     = O[p2][0][r] * inv * G[p2][r];
        og[4 + r] = O[p2][1][r] * inv * G[p2][4 + r];
      }
      U8 OB;   // gated O^T as permuted-k B-frag (k-permutation matches WoA)
      OB.u[0] = pk(og[0],og[1]); OB.u[1] = pk(og[2],og[3]);
      OB.u[2] = pk(og[4],og[5]); OB.u[3] = pk(og[6],og[7]);
      acc[p2][0] = mfma16(WoA0.b, OB.b, acc[p2][0]);   // couts 0..15
      acc[p2][1] = mfma16(WoA1.b, OB.b, acc[p2][1]);   // couts 16..31
    }

    if (h < 3) qg(h + 1);   // Q/G for next head (reads sZ only; after epilogue
                            // so G of head h is consumed before overwrite)
  }

  // ---------------- epilogue: + bo, float4 stores ----------------
  float bo0[4], bo1[4];
#pragma unroll
  for (int r = 0; r < 4; r++) {
    bo0[r] = bo[quad*4 + r];
    bo1[r] = bo[16 + quad*4 + r];
  }
#pragma unroll
  for (int p2 = 0; p2 < 2; p2++) {
    const int pos = (i << 8) + qhalf*128 + (p2*4 + wave)*16 + col;
    float* op = out + pos*32;
    *(float4*)(op + quad*4)      = make_float4(acc[p2][0][0] + bo0[0], acc[p2][0][1] + bo0[1],
                                               acc[p2][0][2] + bo0[2], acc[p2][0][3] + bo0[3]);
    *(float4*)(op + 16 + quad*4) = make_float4(acc[p2][1][0] + bo1[0], acc[p2][1][1] + bo1[1],
                                               acc[p2][1][2] + bo1[2], acc[p2][1][3] + bo1[3]);
  }
}

extern "C" void kernel_launch(void* const* d_in, const int* in_sizes, int n_in,
                              void* d_out, int out_size, void* d_ws, size_t ws_size,
                              hipStream_t stream)
{
  const float* z    = (const float*)d_in[0];
  const float* ln_g = (const float*)d_in[1];
  const float* ln_b = (const float*)d_in[2];
  const float* Wq   = (const float*)d_in[3];
  const float* Wk   = (const float*)d_in[4];
  const float* Wv   = (const float*)d_in[5];
  // d_in[6] = Wb: softmax shift invariance -> exactly cancels, unused.
  const float* Wg   = (const float*)d_in[7];
  const float* bg   = (const float*)d_in[8];
  const float* Wo   = (const float*)d_in[9];
  const float* bo   = (const float*)d_in[10];

  tri_attn_fused<<<dim3(2, 256), 256, 0, stream>>>(z, ln_g, ln_b, Wq, Wk, Wv, Wg, bg, Wo, bo,
                                                   (float*)d_out);
}

// Round 12
// 111.773 us; speedup vs baseline: 1.0139x; 1.0046x over previous
//
#include <hip/hip_runtime.h>

// TriangleAttentionStartingNode — MI355X gfx950. f32 global I/O, bf16 MFMA compute.
//
// R16: l-via-MFMA round. R15's v_cvt_pk_bf16_f32 asm FAILED on HW (max
// output 468 vs O(1) ref — structural bit corruption, not rounding; even an
// operand swap would be self-consistent and correct). pk REVERTED to the
// proven 3-op perm pack (R14 state, ~41us, passed). New single change:
// softmax denominator moved off the VALU onto the idle MFMA pipe (10% util):
// PB is already an MFMA B-operand, so lacc = mfma16(ONES, PB, lacc) gives
// every row = sum over the fragment's 32 keys of P[key][q=col]; accumulated
// over all kb-iters/halves, lacc[0] = full 256-key denominator in every
// lane. Deletes the 7-add tree per kb-iter (448 adds/thread) AND both
// epilogue shfl_xors. l now sums bf16-rounded P (same values PV consumes)
// — more self-consistent, ~2^-9 relative shift, far under tolerance.
//
// Kept from R14: double-buffered sK/sVt (55.8 KB, 2 blk/CU), software-
// pipelined {proj(next half) || attend(current)} across heads, 10 barriers.
// Kept from R12: raw HW transcendentals (exp2f/rcpf/rsqf builtins).
// Kept: grid (2,256), 256 thr; plain __launch_bounds__(256) (2nd arg
// spills, R5/R6); v_perm round-half-up bf16 packing; softmax scale*log2e
// folded into Q; Wb unused (softmax shift invariance).

typedef unsigned short u16;
typedef unsigned int   u32;
typedef __bf16 bf16x8 __attribute__((ext_vector_type(8)));
typedef float  f32x4  __attribute__((ext_vector_type(4)));

union U8 { bf16x8 b; u32 u[4]; };

// round-half-up f32->bf16 pair pack: 2 adds + 1 v_perm (PROVEN; R15's
// cvt_pk asm corrupted outputs on this toolchain — do not revisit blind)
__device__ __forceinline__ u32 pk(float a, float b) {
  const u32 au = __float_as_uint(a) + 0x8000u;
  const u32 bu = __float_as_uint(b) + 0x8000u;
  return __builtin_amdgcn_perm(bu, au, 0x07060302u);  // {b.hi16, a.hi16}
}
__device__ __forceinline__ f32x4 mfma16(bf16x8 a, bf16x8 b, f32x4 c) {
  return __builtin_amdgcn_mfma_f32_16x16x32_bf16(a, b, c, 0, 0, 0);
}
// raw v_exp_f32 (no libm denormal fixup)
__device__ __forceinline__ float ex2(float x) { return __builtin_amdgcn_exp2f(x); }
// sigmoid via v_exp + v_rcp (1 ulp)
__device__ __forceinline__ float sigm(float x) {
  return __builtin_amdgcn_rcpf(1.f + __builtin_amdgcn_exp2f(-1.44269504089f * x));
}

#define LDZ 40    // 80 B rows (16B-aligned uint4 reads)
#define LDK 36    // 72 B rows
#define LDV 132   // 264 B rows

__global__ __launch_bounds__(256) void tri_attn_fused(
    const float* __restrict__ z,  const float* __restrict__ ln_g, const float* __restrict__ ln_b,
    const float* __restrict__ Wq, const float* __restrict__ Wk,   const float* __restrict__ Wv,
    const float* __restrict__ Wg, const float* __restrict__ bg,
    const float* __restrict__ Wo, const float* __restrict__ bo,   float* __restrict__ out)
{
  __shared__ u16 sZ [256][LDZ];       // zn[pos][ch] bf16                  20480 B
  __shared__ u16 sK [2][128][LDK];    // K[key%128][ch]  (double-buffered) 18432 B
  __shared__ u16 sVt[2][32][LDV];     // V^T[ch][key%128](double-buffered) 16896 B

  const int qhalf = blockIdx.x;
  const int i     = blockIdx.y;
  const int tid   = threadIdx.x;
  const int wave  = tid >> 6, lane = tid & 63, quad = lane >> 4, col = lane & 15;
  const f32x4 z4  = {0.f, 0.f, 0.f, 0.f};

  // ---------------- phase 0: LayerNorm (one thread per position) ----------------
  {
    const float* zr = z + (((i << 8) + tid) << 5);
    float x[32];
#pragma unroll
    for (int e = 0; e < 8; e++) {
      const float4 v = *(const float4*)(zr + e*4);
      x[4*e] = v.x; x[4*e+1] = v.y; x[4*e+2] = v.z; x[4*e+3] = v.w;
    }
    float mu = 0.f;
#pragma unroll
    for (int c = 0; c < 32; c++) mu += x[c];
    mu *= (1.f / 32.f);
    float s2 = 0.f;
#pragma unroll
    for (int c = 0; c < 32; c++) { float d = x[c] - mu; s2 += d * d; }
    const float rstd = __builtin_amdgcn_rsqf(s2 * (1.f / 32.f) + 1e-5f);
    u32* dst = (u32*)&sZ[tid][0];
#pragma unroll
    for (int e = 0; e < 16; e++) {
      const float za = (x[2*e]   - mu) * rstd * ln_g[2*e]   + ln_b[2*e];
      const float zb = (x[2*e+1] - mu) * rstd * ln_g[2*e+1] + ln_b[2*e+1];
      dst[e] = pk(za, zb);
    }
  }
  __syncthreads();

  f32x4 acc[2][2] = {{z4, z4}, {z4, z4}};   // fp32 out accumulators (across heads)
  const float k2e = 0.17677669529663687f * 1.44269504089f;   // (1/sqrt32)*log2(e)

  // all-ones bf16 A-fragment for the l-reduction MFMA
  U8 ONESF;
#pragma unroll
  for (int j = 0; j < 4; j++) ONESF.u[j] = 0x3F803F80u;   // bf16 1.0 pairs

  // weight fragments (f32 -> bf16 pack), L1/L2-hot
  auto ldw = [&](const float* W, int h, int cb) -> U8 {
    const float* p = W + h*1024 + (cb*16 + col)*32 + quad*8;
    const float4 a = *(const float4*)(p);
    const float4 b = *(const float4*)(p + 4);
    U8 t;
    t.u[0] = pk(a.x, a.y); t.u[1] = pk(a.z, a.w);
    t.u[2] = pk(b.x, b.y); t.u[3] = pk(b.z, b.w);
    return t;
  };

  U8    QB[2];       // Q (pre-scaled) permuted-k B-frags, per head
  float G[2][8];     // gates, O^T C-layout, per head

  // Q/G for head h: this block's 128 queries (2 tiles/wave); reads sZ only
  auto qg = [&](int h) {
    const U8 WqF0 = ldw(Wq,h,0), WqF1 = ldw(Wq,h,1);
    const U8 WgF0 = ldw(Wg,h,0), WgF1 = ldw(Wg,h,1);
    float bgl[8];
#pragma unroll
    for (int r = 0; r < 4; r++) {
      bgl[r]     = bg[h*32 + quad*4 + r];
      bgl[4 + r] = bg[h*32 + 16 + quad*4 + r];
    }
#pragma unroll
    for (int p2 = 0; p2 < 2; p2++) {
      const int row = qhalf*128 + (p2*4 + wave)*16 + col;
      U8 ZA;
      {
        const uint4 v = *(const uint4*)&sZ[row][quad*8];
        ZA.u[0] = v.x; ZA.u[1] = v.y; ZA.u[2] = v.z; ZA.u[3] = v.w;
      }
      const f32x4 q0 = mfma16(WqF0.b, ZA.b, z4);
      const f32x4 q1 = mfma16(WqF1.b, ZA.b, z4);
      const f32x4 g0 = mfma16(WgF0.b, ZA.b, z4);
      const f32x4 g1 = mfma16(WgF1.b, ZA.b, z4);
      QB[p2].u[0] = pk(q0[0]*k2e, q0[1]*k2e); QB[p2].u[1] = pk(q0[2]*k2e, q0[3]*k2e);
      QB[p2].u[2] = pk(q1[0]*k2e, q1[1]*k2e); QB[p2].u[3] = pk(q1[2]*k2e, q1[3]*k2e);
#pragma unroll
      for (int r = 0; r < 4; r++) {
        G[p2][r]     = sigm(g0[r] + bgl[r]);
        G[p2][4 + r] = sigm(g1[r] + bgl[4 + r]);
      }
    }
  };

  // project keys m*128..m*128+127 into buffer buf (reads sZ only)
  auto proj = [&](const U8& K0w, const U8& K1w, const U8& V0w, const U8& V1w,
                  int m, int buf) {
#pragma unroll
    for (int pp = 0; pp < 2; pp++) {
      const int lbase = (pp*4 + wave) * 16;        // local key base (0..112)
      const int grow  = m*128 + lbase + col;       // global position
      U8 ZA;
      {
        const uint4 v = *(const uint4*)&sZ[grow][quad*8];
        ZA.u[0] = v.x; ZA.u[1] = v.y; ZA.u[2] = v.z; ZA.u[3] = v.w;
      }
      // K^T (C-layout: ch=quad*4+reg, key=col), V (key=quad*4+reg, ch=col)
      const f32x4 k0 = mfma16(K0w.b, ZA.b, z4);
      const f32x4 k1 = mfma16(K1w.b, ZA.b, z4);
      const f32x4 v0 = mfma16(ZA.b, V0w.b, z4);
      const f32x4 v1 = mfma16(ZA.b, V1w.b, z4);
      *(uint2*)&sK[buf][lbase + col][quad*4]        = make_uint2(pk(k0[0],k0[1]), pk(k0[2],k0[3]));
      *(uint2*)&sK[buf][lbase + col][16 + quad*4]   = make_uint2(pk(k1[0],k1[1]), pk(k1[2],k1[3]));
      *(uint2*)&sVt[buf][col][lbase + quad*4]       = make_uint2(pk(v0[0],v0[1]), pk(v0[2],v0[3]));
      *(uint2*)&sVt[buf][16 + col][lbase + quad*4]  = make_uint2(pk(v1[0],v1[1]), pk(v1[2],v1[3]));
    }
  };

  // -------- prologue: head 0 Q/G + first half projection --------
  U8 KC0 = ldw(Wk,0,0), KC1 = ldw(Wk,0,1);   // current head's K/V weight frags
  U8 VC0 = ldw(Wv,0,0), VC1 = ldw(Wv,0,1);
  qg(0);
  proj(KC0, KC1, VC0, VC1, 0, 0);
  __syncthreads();

  for (int h = 0; h < 4; ++h) {
    f32x4 lacc[2] = {z4, z4};               // l via ONES-MFMA: rows identical
    f32x4 O[2][2] = {{z4, z4}, {z4, z4}};   // O^T per p2: ch=quad*4+r (+16), q=col

    // attention over one buffered half (p2 outer, kb inner)
    auto attend = [&](int buf) {
#pragma unroll
      for (int p2 = 0; p2 < 2; p2++) {
#pragma unroll
        for (int kb = 0; kb < 128; kb += 32) {
          U8 KF0, KF1;
          {
            const uint2 a = *(const uint2*)&sK[buf][kb + col][quad*4];
            const uint2 b = *(const uint2*)&sK[buf][kb + col][16 + quad*4];
            KF0.u[0] = a.x; KF0.u[1] = a.y; KF0.u[2] = b.x; KF0.u[3] = b.y;
            const uint2 c = *(const uint2*)&sK[buf][kb + 16 + col][quad*4];
            const uint2 d = *(const uint2*)&sK[buf][kb + 16 + col][16 + quad*4];
            KF1.u[0] = c.x; KF1.u[1] = c.y; KF1.u[2] = d.x; KF1.u[3] = d.y;
          }
          const f32x4 S0 = mfma16(KF0.b, QB[p2].b, z4);   // keys kb+quad*4+r
          const f32x4 S1 = mfma16(KF1.b, QB[p2].b, z4);   // keys kb+16+quad*4+r
          float ps[8];
#pragma unroll
          for (int r = 0; r < 4; r++) {
            ps[r]     = ex2(S0[r]);     // scale pre-folded into Q; raw v_exp_f32
            ps[4 + r] = ex2(S1[r]);
          }
          U8 PB;
          PB.u[0] = pk(ps[0],ps[1]); PB.u[1] = pk(ps[2],ps[3]);
          PB.u[2] = pk(ps[4],ps[5]); PB.u[3] = pk(ps[6],ps[7]);
          // l on the MFMA pipe: every row of lacc = sum over these 32 keys
          lacc[p2] = mfma16(ONESF.b, PB.b, lacc[p2]);
          U8 VF0, VF1;
          {
            const uint2 a = *(const uint2*)&sVt[buf][col][kb + quad*4];
            const uint2 b = *(const uint2*)&sVt[buf][col][kb + 16 + quad*4];
            VF0.u[0] = a.x; VF0.u[1] = a.y; VF0.u[2] = b.x; VF0.u[3] = b.y;
            const uint2 c = *(const uint2*)&sVt[buf][16 + col][kb + quad*4];
            const uint2 d = *(const uint2*)&sVt[buf][16 + col][kb + 16 + quad*4];
            VF1.u[0] = c.x; VF1.u[1] = c.y; VF1.u[2] = d.x; VF1.u[3] = d.y;
          }
          O[p2][0] = mfma16(VF0.b, PB.b, O[p2][0]);
          O[p2][1] = mfma16(VF1.b, PB.b, O[p2][1]);
        }
      }
    };

    // ---- stage A: proj(head h, half 1 -> buf1) overlapped with attend(buf0) ----
    proj(KC0, KC1, VC0, VC1, 1, 1);
    attend(0);
    __syncthreads();   // buf1 ready; buf0 free

    // ---- stage B: proj(head h+1, half 0 -> buf0) overlapped with attend(buf1) ----
    if (h < 3) {
      const U8 KN0 = ldw(Wk,h+1,0), KN1 = ldw(Wk,h+1,1);
      const U8 VN0 = ldw(Wv,h+1,0), VN1 = ldw(Wv,h+1,1);
      proj(KN0, KN1, VN0, VN1, 0, 0);
      KC0 = KN0; KC1 = KN1; VC0 = VN0; VC1 = VN1;
    }
    attend(1);
    __syncthreads();   // buf0 ready for next head; buf1 free

    // -------- epilogue: normalize, gate, fused out-projection (regs only) --------
    U8 WoA0, WoA1;   // Wo A-frags with matching k-permutation (qt-invariant)
    {
      const float4 a = *(const float4*)(Wo + col*128 + h*32 + quad*4);
      const float4 b = *(const float4*)(Wo + col*128 + h*32 + 16 + quad*4);
      WoA0.u[0] = pk(a.x,a.y); WoA0.u[1] = pk(a.z,a.w);
      WoA0.u[2] = pk(b.x,b.y); WoA0.u[3] = pk(b.z,b.w);
      const float4 c = *(const float4*)(Wo + (16 + col)*128 + h*32 + quad*4);
      const float4 d = *(const float4*)(Wo + (16 + col)*128 + h*32 + 16 + quad*4);
      WoA1.u[0] = pk(c.x,c.y); WoA1.u[1] = pk(c.z,c.w);
      WoA1.u[2] = pk(d.x,d.y); WoA1.u[3] = pk(d.z,d.w);
    }
#pragma unroll
    for (int p2 = 0; p2 < 2; p2++) {
      const float inv = __builtin_amdgcn_rcpf(lacc[p2][0]);   // full 256-key sum
      float og[8];
#pragma unroll
      for (int r = 0; r < 4; r++) {
        og[r]     = O[p2][0][r] * inv * G[p2][r];
        og[4 + r] = O[p2][1][r] * inv * G[p2][4 + r];
      }
      U8 OB;   // gated O^T as permuted-k B-frag (k-permutation matches WoA)
      OB.u[0] = pk(og[0],og[1]); OB.u[1] = pk(og[2],og[3]);
      OB.u[2] = pk(og[4],og[5]); OB.u[3] = pk(og[6],og[7]);
      acc[p2][0] = mfma16(WoA0.b, OB.b, acc[p2][0]);   // couts 0..15
      acc[p2][1] = mfma16(WoA1.b, OB.b, acc[p2][1]);   // couts 16..31
    }

    if (h < 3) qg(h + 1);   // Q/G for next head (reads sZ only; after epilogue
                            // so G of head h is consumed before overwrite)
  }

  // ---------------- epilogue: + bo, float4 stores ----------------
  float bo0[4], bo1[4];
#pragma unroll
  for (int r = 0; r < 4; r++) {
    bo0[r] = bo[quad*4 + r];
    bo1[r] = bo[16 + quad*4 + r];
  }
#pragma unroll
  for (int p2 = 0; p2 < 2; p2++) {
    const int pos = (i << 8) + qhalf*128 + (p2*4 + wave)*16 + col;
    float* op = out + pos*32;
    *(float4*)(op + quad*4)      = make_float4(acc[p2][0][0] + bo0[0], acc[p2][0][1] + bo0[1],
                                               acc[p2][0][2] + bo0[2], acc[p2][0][3] + bo0[3]);
    *(float4*)(op + 16 + quad*4) = make_float4(acc[p2][1][0] + bo1[0], acc[p2][1][1] + bo1[1],
                                               acc[p2][1][2] + bo1[2], acc[p2][1][3] + bo1[3]);
  }
}

extern "C" void kernel_launch(void* const* d_in, const int* in_sizes, int n_in,
                              void* d_out, int out_size, void* d_ws, size_t ws_size,
                              hipStream_t stream)
{
  const float* z    = (const float*)d_in[0];
  const float* ln_g = (const float*)d_in[1];
  const float* ln_b = (const float*)d_in[2];
  const float* Wq   = (const float*)d_in[3];
  const float* Wk   = (const float*)d_in[4];
  const float* Wv   = (const float*)d_in[5];
  // d_in[6] = Wb: softmax shift invariance -> exactly cancels, unused.
  const float* Wg   = (const float*)d_in[7];
  const float* bg   = (const float*)d_in[8];
  const float* Wo   = (const float*)d_in[9];
  const float* bo   = (const float*)d_in[10];

  tri_attn_fused<<<dim3(2, 256), 256, 0, stream>>>(z, ln_g, ln_b, Wq, Wk, Wv, Wg, bg, Wo, bo,
                                                   (float*)d_out);
}

// Round 13
// 105.493 us; speedup vs baseline: 1.0743x; 1.0595x over previous
//
#include <hip/hip_runtime.h>

// TriangleAttentionStartingNode — MI355X gfx950. f32 global I/O, bf16 MFMA compute.
//
// R17: weight-prepack round. R16's null (l-add-tree removal, ~450 off-path
// VALU, flat at ~42.5us) + R13 null + R12 win (−18%, removed instrs INSIDE
// the S->exp->P chain) falsify the issue-slot model: the kernel is
// CRITICAL-PATH bound. Last big off-path-but-chain-heading block: weight
// fragment construction — ~40 ldw/wave x (2 global f32 loads + 4 packs)
// ~700 instrs, each at the head of a phase's dependency chain. Fix: tiny
// prepack kernel (10 blk x 256 thr, 40KB -> d_ws, ~2us) pre-converts ALL
// Wq/Wk/Wv/Wg/Wo fragments to bf16 in the exact per-lane layout consumed;
// main-kernel ldw = one L2-hot global_load_dwordx4. Wq pre-scaled by
// (1/sqrt32)*log2e in prepack (deletes qg's 16 muls/head; <=1ulp reroute,
// 3x threshold headroom). Fallback (ws_size<40960) keeps old path via
// if constexpr. Everything else = R16.
//
// Kept from R16: l via ONES-MFMA (lacc) — fewer instrs, passed.
// Kept from R14: double-buffered sK/sVt (55.8 KB), {proj || attend}
// software pipeline across heads, 10 barriers.
// Kept from R12: raw HW transcendentals (exp2f/rcpf/rsqf builtins).
// Kept: grid (2,256), 256 thr; plain __launch_bounds__(256) (2nd arg
// spills, R5/R6); v_perm round-half-up bf16 pack (R15's cvt_pk asm
// corrupted outputs — closed); Wb unused (softmax shift invariance).

typedef unsigned short u16;
typedef unsigned int   u32;
typedef __bf16 bf16x8 __attribute__((ext_vector_type(8)));
typedef float  f32x4  __attribute__((ext_vector_type(4)));

union U8 { bf16x8 b; u32 u[4]; };

// round-half-up f32->bf16 pair pack: 2 adds + 1 v_perm (proven)
__device__ __forceinline__ u32 pk(float a, float b) {
  const u32 au = __float_as_uint(a) + 0x8000u;
  const u32 bu = __float_as_uint(b) + 0x8000u;
  return __builtin_amdgcn_perm(bu, au, 0x07060302u);  // {b.hi16, a.hi16}
}
__device__ __forceinline__ f32x4 mfma16(bf16x8 a, bf16x8 b, f32x4 c) {
  return __builtin_amdgcn_mfma_f32_16x16x32_bf16(a, b, c, 0, 0, 0);
}
// raw v_exp_f32 (no libm denormal fixup)
__device__ __forceinline__ float ex2(float x) { return __builtin_amdgcn_exp2f(x); }
// sigmoid via v_exp + v_rcp (1 ulp)
__device__ __forceinline__ float sigm(float x) {
  return __builtin_amdgcn_rcpf(1.f + __builtin_amdgcn_exp2f(-1.44269504089f * x));
}

#define LDZ 40    // 80 B rows (16B-aligned uint4 reads)
#define LDK 36    // 72 B rows
#define LDV 132   // 264 B rows

// ---------------- prepack: all weight fragments -> bf16 in d_ws ----------------
// ws layout (uint4 units): [mat 0..3][h 0..3][cb 0..1][lane] at
// (mat*8 + h*2 + cb)*64 + lane; Wo at (32 + h*2 + half)*64 + lane.
// 40 groups x 64 lanes x 16B = 40960 B.
__global__ __launch_bounds__(256) void prepack_w(
    const float* __restrict__ Wq, const float* __restrict__ Wk,
    const float* __restrict__ Wv, const float* __restrict__ Wg,
    const float* __restrict__ Wo, uint4* __restrict__ ws)
{
  const int t    = blockIdx.x * 256 + threadIdx.x;    // 0..2559
  const int lane = t & 63;
  const int quad = lane >> 4, col = lane & 15;
  const int fid  = t >> 6;                            // 0..39
  const float k2e = 0.17677669529663687f * 1.44269504089f;
  U8 f;
  if (fid < 32) {
    const int mat = fid >> 3, h = (fid >> 1) & 3, cb = fid & 1;
    const float* W = (mat == 0) ? Wq : (mat == 1) ? Wk : (mat == 2) ? Wv : Wg;
    const float s  = (mat == 0) ? k2e : 1.f;          // softmax scale folded into Wq
    const float* p = W + h*1024 + (cb*16 + col)*32 + quad*8;
    const float4 a = *(const float4*)(p);
    const float4 b = *(const float4*)(p + 4);
    f.u[0] = pk(a.x*s, a.y*s); f.u[1] = pk(a.z*s, a.w*s);
    f.u[2] = pk(b.x*s, b.y*s); f.u[3] = pk(b.z*s, b.w*s);
  } else {
    const int g = fid - 32, h = g >> 1, hf = g & 1;
    const float* p = Wo + (hf*16 + col)*128 + h*32 + quad*4;
    const float4 a = *(const float4*)(p);
    const float4 b = *(const float4*)(p + 16);
    f.u[0] = pk(a.x,a.y); f.u[1] = pk(a.z,a.w);
    f.u[2] = pk(b.x,b.y); f.u[3] = pk(b.z,b.w);
  }
  ws[fid*64 + lane] = *(const uint4*)f.u;
}

template <bool PP>
__global__ __launch_bounds__(256) void tri_attn_fused(
    const float* __restrict__ z,  const float* __restrict__ ln_g, const float* __restrict__ ln_b,
    const float* __restrict__ Wq, const float* __restrict__ Wk,   const float* __restrict__ Wv,
    const float* __restrict__ Wg, const float* __restrict__ bg,
    const float* __restrict__ Wo, const float* __restrict__ bo,
    const uint4* __restrict__ wsf, float* __restrict__ out)
{
  __shared__ u16 sZ [256][LDZ];       // zn[pos][ch] bf16                  20480 B
  __shared__ u16 sK [2][128][LDK];    // K[key%128][ch]  (double-buffered) 18432 B
  __shared__ u16 sVt[2][32][LDV];     // V^T[ch][key%128](double-buffered) 16896 B

  const int qhalf = blockIdx.x;
  const int i     = blockIdx.y;
  const int tid   = threadIdx.x;
  const int wave  = tid >> 6, lane = tid & 63, quad = lane >> 4, col = lane & 15;
  const f32x4 z4  = {0.f, 0.f, 0.f, 0.f};

  // ---------------- phase 0: LayerNorm (one thread per position) ----------------
  {
    const float* zr = z + (((i << 8) + tid) << 5);
    float x[32];
#pragma unroll
    for (int e = 0; e < 8; e++) {
      const float4 v = *(const float4*)(zr + e*4);
      x[4*e] = v.x; x[4*e+1] = v.y; x[4*e+2] = v.z; x[4*e+3] = v.w;
    }
    float mu = 0.f;
#pragma unroll
    for (int c = 0; c < 32; c++) mu += x[c];
    mu *= (1.f / 32.f);
    float s2 = 0.f;
#pragma unroll
    for (int c = 0; c < 32; c++) { float d = x[c] - mu; s2 += d * d; }
    const float rstd = __builtin_amdgcn_rsqf(s2 * (1.f / 32.f) + 1e-5f);
    u32* dst = (u32*)&sZ[tid][0];
#pragma unroll
    for (int e = 0; e < 16; e++) {
      const float za = (x[2*e]   - mu) * rstd * ln_g[2*e]   + ln_b[2*e];
      const float zb = (x[2*e+1] - mu) * rstd * ln_g[2*e+1] + ln_b[2*e+1];
      dst[e] = pk(za, zb);
    }
  }
  __syncthreads();

  f32x4 acc[2][2] = {{z4, z4}, {z4, z4}};   // fp32 out accumulators (across heads)
  const float k2e = 0.17677669529663687f * 1.44269504089f;   // (1/sqrt32)*log2(e)

  // all-ones bf16 A-fragment for the l-reduction MFMA
  U8 ONESF;
#pragma unroll
  for (int j = 0; j < 4; j++) ONESF.u[j] = 0x3F803F80u;   // bf16 1.0 pairs

  // weight fragment loader: prepacked 16B load (PP) or f32 load + pack
  auto ldw = [&](int mat, int h, int cb) -> U8 {
    U8 t;
    if constexpr (PP) {
      *(uint4*)t.u = wsf[(mat*8 + h*2 + cb)*64 + lane];
    } else {
      const float* W = (mat==0) ? Wq : (mat==1) ? Wk : (mat==2) ? Wv : Wg;
      const float* p = W + h*1024 + (cb*16 + col)*32 + quad*8;
      const float4 a = *(const float4*)(p);
      const float4 b = *(const float4*)(p + 4);
      t.u[0] = pk(a.x, a.y); t.u[1] = pk(a.z, a.w);
      t.u[2] = pk(b.x, b.y); t.u[3] = pk(b.z, b.w);
    }
    return t;
  };

  U8    QB[2];       // Q (pre-scaled) permuted-k B-frags, per head
  float G[2][8];     // gates, O^T C-layout, per head

  // Q/G for head h: this block's 128 queries (2 tiles/wave); reads sZ only
  auto qg = [&](int h) {
    const U8 WqF0 = ldw(0,h,0), WqF1 = ldw(0,h,1);
    const U8 WgF0 = ldw(3,h,0), WgF1 = ldw(3,h,1);
    float bgl[8];
#pragma unroll
    for (int r = 0; r < 4; r++) {
      bgl[r]     = bg[h*32 + quad*4 + r];
      bgl[4 + r] = bg[h*32 + 16 + quad*4 + r];
    }
#pragma unroll
    for (int p2 = 0; p2 < 2; p2++) {
      const int row = qhalf*128 + (p2*4 + wave)*16 + col;
      U8 ZA;
      {
        const uint4 v = *(const uint4*)&sZ[row][quad*8];
        ZA.u[0] = v.x; ZA.u[1] = v.y; ZA.u[2] = v.z; ZA.u[3] = v.w;
      }
      const f32x4 q0 = mfma16(WqF0.b, ZA.b, z4);
      const f32x4 q1 = mfma16(WqF1.b, ZA.b, z4);
      const f32x4 g0 = mfma16(WgF0.b, ZA.b, z4);
      const f32x4 g1 = mfma16(WgF1.b, ZA.b, z4);
      if constexpr (PP) {   // scale already folded into Wq by prepack
        QB[p2].u[0] = pk(q0[0], q0[1]); QB[p2].u[1] = pk(q0[2], q0[3]);
        QB[p2].u[2] = pk(q1[0], q1[1]); QB[p2].u[3] = pk(q1[2], q1[3]);
      } else {
        QB[p2].u[0] = pk(q0[0]*k2e, q0[1]*k2e); QB[p2].u[1] = pk(q0[2]*k2e, q0[3]*k2e);
        QB[p2].u[2] = pk(q1[0]*k2e, q1[1]*k2e); QB[p2].u[3] = pk(q1[2]*k2e, q1[3]*k2e);
      }
#pragma unroll
      for (int r = 0; r < 4; r++) {
        G[p2][r]     = sigm(g0[r] + bgl[r]);
        G[p2][4 + r] = sigm(g1[r] + bgl[4 + r]);
      }
    }
  };

  // project keys m*128..m*128+127 into buffer buf (reads sZ only)
  auto proj = [&](const U8& K0w, const U8& K1w, const U8& V0w, const U8& V1w,
                  int m, int buf) {
#pragma unroll
    for (int pp = 0; pp < 2; pp++) {
      const int lbase = (pp*4 + wave) * 16;        // local key base (0..112)
      const int grow  = m*128 + lbase + col;       // global position
      U8 ZA;
      {
        const uint4 v = *(const uint4*)&sZ[grow][quad*8];
        ZA.u[0] = v.x; ZA.u[1] = v.y; ZA.u[2] = v.z; ZA.u[3] = v.w;
      }
      // K^T (C-layout: ch=quad*4+reg, key=col), V (key=quad*4+reg, ch=col)
      const f32x4 k0 = mfma16(K0w.b, ZA.b, z4);
      const f32x4 k1 = mfma16(K1w.b, ZA.b, z4);
      const f32x4 v0 = mfma16(ZA.b, V0w.b, z4);
      const f32x4 v1 = mfma16(ZA.b, V1w.b, z4);
      *(uint2*)&sK[buf][lbase + col][quad*4]        = make_uint2(pk(k0[0],k0[1]), pk(k0[2],k0[3]));
      *(uint2*)&sK[buf][lbase + col][16 + quad*4]   = make_uint2(pk(k1[0],k1[1]), pk(k1[2],k1[3]));
      *(uint2*)&sVt[buf][col][lbase + quad*4]       = make_uint2(pk(v0[0],v0[1]), pk(v0[2],v0[3]));
      *(uint2*)&sVt[buf][16 + col][lbase + quad*4]  = make_uint2(pk(v1[0],v1[1]), pk(v1[2],v1[3]));
    }
  };

  // -------- prologue: head 0 Q/G + first half projection --------
  U8 KC0 = ldw(1,0,0), KC1 = ldw(1,0,1);   // current head's K/V weight frags
  U8 VC0 = ldw(2,0,0), VC1 = ldw(2,0,1);
  qg(0);
  proj(KC0, KC1, VC0, VC1, 0, 0);
  __syncthreads();

  for (int h = 0; h < 4; ++h) {
    f32x4 lacc[2] = {z4, z4};               // l via ONES-MFMA: rows identical
    f32x4 O[2][2] = {{z4, z4}, {z4, z4}};   // O^T per p2: ch=quad*4+r (+16), q=col

    // attention over one buffered half (p2 outer, kb inner)
    auto attend = [&](int buf) {
#pragma unroll
      for (int p2 = 0; p2 < 2; p2++) {
#pragma unroll
        for (int kb = 0; kb < 128; kb += 32) {
          U8 KF0, KF1;
          {
            const uint2 a = *(const uint2*)&sK[buf][kb + col][quad*4];
            const uint2 b = *(const uint2*)&sK[buf][kb + col][16 + quad*4];
            KF0.u[0] = a.x; KF0.u[1] = a.y; KF0.u[2] = b.x; KF0.u[3] = b.y;
            const uint2 c = *(const uint2*)&sK[buf][kb + 16 + col][quad*4];
            const uint2 d = *(const uint2*)&sK[buf][kb + 16 + col][16 + quad*4];
            KF1.u[0] = c.x; KF1.u[1] = c.y; KF1.u[2] = d.x; KF1.u[3] = d.y;
          }
          const f32x4 S0 = mfma16(KF0.b, QB[p2].b, z4);   // keys kb+quad*4+r
          const f32x4 S1 = mfma16(KF1.b, QB[p2].b, z4);   // keys kb+16+quad*4+r
          float ps[8];
#pragma unroll
          for (int r = 0; r < 4; r++) {
            ps[r]     = ex2(S0[r]);     // scale pre-folded into Q; raw v_exp_f32
            ps[4 + r] = ex2(S1[r]);
          }
          U8 PB;
          PB.u[0] = pk(ps[0],ps[1]); PB.u[1] = pk(ps[2],ps[3]);
          PB.u[2] = pk(ps[4],ps[5]); PB.u[3] = pk(ps[6],ps[7]);
          // l on the MFMA pipe: every row of lacc = sum over these 32 keys
          lacc[p2] = mfma16(ONESF.b, PB.b, lacc[p2]);
          U8 VF0, VF1;
          {
            const uint2 a = *(const uint2*)&sVt[buf][col][kb + quad*4];
            const uint2 b = *(const uint2*)&sVt[buf][col][kb + 16 + quad*4];
            VF0.u[0] = a.x; VF0.u[1] = a.y; VF0.u[2] = b.x; VF0.u[3] = b.y;
            const uint2 c = *(const uint2*)&sVt[buf][16 + col][kb + quad*4];
            const uint2 d = *(const uint2*)&sVt[buf][16 + col][kb + 16 + quad*4];
            VF1.u[0] = c.x; VF1.u[1] = c.y; VF1.u[2] = d.x; VF1.u[3] = d.y;
          }
          O[p2][0] = mfma16(VF0.b, PB.b, O[p2][0]);
          O[p2][1] = mfma16(VF1.b, PB.b, O[p2][1]);
        }
      }
    };

    // ---- stage A: proj(head h, half 1 -> buf1) overlapped with attend(buf0) ----
    proj(KC0, KC1, VC0, VC1, 1, 1);
    attend(0);
    __syncthreads();   // buf1 ready; buf0 free

    // ---- stage B: proj(head h+1, half 0 -> buf0) overlapped with attend(buf1) ----
    if (h < 3) {
      const U8 KN0 = ldw(1,h+1,0), KN1 = ldw(1,h+1,1);
      const U8 VN0 = ldw(2,h+1,0), VN1 = ldw(2,h+1,1);
      proj(KN0, KN1, VN0, VN1, 0, 0);
      KC0 = KN0; KC1 = KN1; VC0 = VN0; VC1 = VN1;
    }
    attend(1);
    __syncthreads();   // buf0 ready for next head; buf1 free

    // -------- epilogue: normalize, gate, fused out-projection (regs only) --------
    U8 WoA0, WoA1;   // Wo A-frags with matching k-permutation (qt-invariant)
    if constexpr (PP) {
      *(uint4*)WoA0.u = wsf[(32 + h*2 + 0)*64 + lane];
      *(uint4*)WoA1.u = wsf[(32 + h*2 + 1)*64 + lane];
    } else {
      const float4 a = *(const float4*)(Wo + col*128 + h*32 + quad*4);
      const float4 b = *(const float4*)(Wo + col*128 + h*32 + 16 + quad*4);
      WoA0.u[0] = pk(a.x,a.y); WoA0.u[1] = pk(a.z,a.w);
      WoA0.u[2] = pk(b.x,b.y); WoA0.u[3] = pk(b.z,b.w);
      const float4 c = *(const float4*)(Wo + (16 + col)*128 + h*32 + quad*4);
      const float4 d = *(const float4*)(Wo + (16 + col)*128 + h*32 + 16 + quad*4);
      WoA1.u[0] = pk(c.x,c.y); WoA1.u[1] = pk(c.z,c.w);
      WoA1.u[2] = pk(d.x,d.y); WoA1.u[3] = pk(d.z,d.w);
    }
#pragma unroll
    for (int p2 = 0; p2 < 2; p2++) {
      const float inv = __builtin_amdgcn_rcpf(lacc[p2][0]);   // full 256-key sum
      float og[8];
#pragma unroll
      for (int r = 0; r < 4; r++) {
        og[r]     = O[p2][0][r] * inv * G[p2][r];
        og[4 + r] = O[p2][1][r] * inv * G[p2][4 + r];
      }
      U8 OB;   // gated O^T as permuted-k B-frag (k-permutation matches WoA)
      OB.u[0] = pk(og[0],og[1]); OB.u[1] = pk(og[2],og[3]);
      OB.u[2] = pk(og[4],og[5]); OB.u[3] = pk(og[6],og[7]);
      acc[p2][0] = mfma16(WoA0.b, OB.b, acc[p2][0]);   // couts 0..15
      acc[p2][1] = mfma16(WoA1.b, OB.b, acc[p2][1]);   // couts 16..31
    }

    if (h < 3) qg(h + 1);   // Q/G for next head (reads sZ only; after epilogue
                            // so G of head h is consumed before overwrite)
  }

  // ---------------- epilogue: + bo, float4 stores ----------------
  float bo0[4], bo1[4];
#pragma unroll
  for (int r = 0; r < 4; r++) {
    bo0[r] = bo[quad*4 + r];
    bo1[r] = bo[16 + quad*4 + r];
  }
#pragma unroll
  for (int p2 = 0; p2 < 2; p2++) {
    const int pos = (i << 8) + qhalf*128 + (p2*4 + wave)*16 + col;
    float* op = out + pos*32;
    *(float4*)(op + quad*4)      = make_float4(acc[p2][0][0] + bo0[0], acc[p2][0][1] + bo0[1],
                                               acc[p2][0][2] + bo0[2], acc[p2][0][3] + bo0[3]);
    *(float4*)(op + 16 + quad*4) = make_float4(acc[p2][1][0] + bo1[0], acc[p2][1][1] + bo1[1],
                                               acc[p2][1][2] + bo1[2], acc[p2][1][3] + bo1[3]);
  }
}

extern "C" void kernel_launch(void* const* d_in, const int* in_sizes, int n_in,
                              void* d_out, int out_size, void* d_ws, size_t ws_size,
                              hipStream_t stream)
{
  const float* z    = (const float*)d_in[0];
  const float* ln_g = (const float*)d_in[1];
  const float* ln_b = (const float*)d_in[2];
  const float* Wq   = (const float*)d_in[3];
  const float* Wk   = (const float*)d_in[4];
  const float* Wv   = (const float*)d_in[5];
  // d_in[6] = Wb: softmax shift invariance -> exactly cancels, unused.
  const float* Wg   = (const float*)d_in[7];
  const float* bg   = (const float*)d_in[8];
  const float* Wo   = (const float*)d_in[9];
  const float* bo   = (const float*)d_in[10];

  if (ws_size >= 40960) {
    prepack_w<<<dim3(10), 256, 0, stream>>>(Wq, Wk, Wv, Wg, Wo, (uint4*)d_ws);
    tri_attn_fused<true><<<dim3(2, 256), 256, 0, stream>>>(
        z, ln_g, ln_b, Wq, Wk, Wv, Wg, bg, Wo, bo, (const uint4*)d_ws, (float*)d_out);
  } else {
    tri_attn_fused<false><<<dim3(2, 256), 256, 0, stream>>>(
        z, ln_g, ln_b, Wq, Wk, Wv, Wg, bg, Wo, bo, (const uint4*)d_ws, (float*)d_out);
  }
}

// Round 14
// 105.421 us; speedup vs baseline: 1.0750x; 1.0007x over previous
//
#include <hip/hip_runtime.h>

// TriangleAttentionStartingNode — MI355X gfx950. f32 global I/O, bf16 MFMA compute.
//
// R18: attend-prefetch round. R17 (weight prepack) won −6us -> kernel
// ~36.5us, confirming model v3: bound by EXPOSED LATENCY on the critical
// path (VMEM chain removal R17 −6us, in-chain VALU R12 −9us; issue-slot
// cuts R16, LDS-count cuts R13, occupancy R9 all null/negative). Next
// largest exposed latency: attend's per-iteration ds_read->S-MFMA heads
// (8 ds_read_b64 ~120cyc x 64 kb-iters/wave; VGPR 104 << 128 says the
// compiler is not hoisting across the exp2/pack tail). Change: explicit
// 2-slot software pipeline in attend — issue kb+1's 8 loads before
// computing kb; slot index kb&1 is compile-time-constant after full unroll
// (rule: no runtime-indexed reg arrays). +16 net VGPR (~120 < 128 cliff).
// Everything else = R17.
//
// Kept from R17: weight prepack kernel (40KB d_ws, bf16 frags in consumer
// layout, Wq pre-scaled by (1/sqrt32)*log2e); fallback path via
// if constexpr (ws_size < 40960).
// Kept from R16: l via ONES-MFMA (lacc). Kept from R14: double-buffered
// sK/sVt, {proj || attend} pipeline across heads, 10 barriers. Kept from
// R12: raw HW transcendentals. Kept: grid (2,256), 256 thr; plain
// __launch_bounds__(256); v_perm round-half-up pack (R15 cvt_pk asm
// corrupted outputs — closed); Wb unused (softmax shift invariance).

typedef unsigned short u16;
typedef unsigned int   u32;
typedef __bf16 bf16x8 __attribute__((ext_vector_type(8)));
typedef float  f32x4  __attribute__((ext_vector_type(4)));

union U8 { bf16x8 b; u32 u[4]; };

// round-half-up f32->bf16 pair pack: 2 adds + 1 v_perm (proven)
__device__ __forceinline__ u32 pk(float a, float b) {
  const u32 au = __float_as_uint(a) + 0x8000u;
  const u32 bu = __float_as_uint(b) + 0x8000u;
  return __builtin_amdgcn_perm(bu, au, 0x07060302u);  // {b.hi16, a.hi16}
}
__device__ __forceinline__ f32x4 mfma16(bf16x8 a, bf16x8 b, f32x4 c) {
  return __builtin_amdgcn_mfma_f32_16x16x32_bf16(a, b, c, 0, 0, 0);
}
// raw v_exp_f32 (no libm denormal fixup)
__device__ __forceinline__ float ex2(float x) { return __builtin_amdgcn_exp2f(x); }
// sigmoid via v_exp + v_rcp (1 ulp)
__device__ __forceinline__ float sigm(float x) {
  return __builtin_amdgcn_rcpf(1.f + __builtin_amdgcn_exp2f(-1.44269504089f * x));
}

#define LDZ 40    // 80 B rows (16B-aligned uint4 reads)
#define LDK 36    // 72 B rows
#define LDV 132   // 264 B rows

// ---------------- prepack: all weight fragments -> bf16 in d_ws ----------------
// ws layout (uint4 units): [mat 0..3][h 0..3][cb 0..1][lane] at
// (mat*8 + h*2 + cb)*64 + lane; Wo at (32 + h*2 + half)*64 + lane.
// 40 groups x 64 lanes x 16B = 40960 B.
__global__ __launch_bounds__(256) void prepack_w(
    const float* __restrict__ Wq, const float* __restrict__ Wk,
    const float* __restrict__ Wv, const float* __restrict__ Wg,
    const float* __restrict__ Wo, uint4* __restrict__ ws)
{
  const int t    = blockIdx.x * 256 + threadIdx.x;    // 0..2559
  const int lane = t & 63;
  const int quad = lane >> 4, col = lane & 15;
  const int fid  = t >> 6;                            // 0..39
  const float k2e = 0.17677669529663687f * 1.44269504089f;
  U8 f;
  if (fid < 32) {
    const int mat = fid >> 3, h = (fid >> 1) & 3, cb = fid & 1;
    const float* W = (mat == 0) ? Wq : (mat == 1) ? Wk : (mat == 2) ? Wv : Wg;
    const float s  = (mat == 0) ? k2e : 1.f;          // softmax scale folded into Wq
    const float* p = W + h*1024 + (cb*16 + col)*32 + quad*8;
    const float4 a = *(const float4*)(p);
    const float4 b = *(const float4*)(p + 4);
    f.u[0] = pk(a.x*s, a.y*s); f.u[1] = pk(a.z*s, a.w*s);
    f.u[2] = pk(b.x*s, b.y*s); f.u[3] = pk(b.z*s, b.w*s);
  } else {
    const int g = fid - 32, h = g >> 1, hf = g & 1;
    const float* p = Wo + (hf*16 + col)*128 + h*32 + quad*4;
    const float4 a = *(const float4*)(p);
    const float4 b = *(const float4*)(p + 16);
    f.u[0] = pk(a.x,a.y); f.u[1] = pk(a.z,a.w);
    f.u[2] = pk(b.x,b.y); f.u[3] = pk(b.z,b.w);
  }
  ws[fid*64 + lane] = *(const uint4*)f.u;
}

template <bool PP>
__global__ __launch_bounds__(256) void tri_attn_fused(
    const float* __restrict__ z,  const float* __restrict__ ln_g, const float* __restrict__ ln_b,
    const float* __restrict__ Wq, const float* __restrict__ Wk,   const float* __restrict__ Wv,
    const float* __restrict__ Wg, const float* __restrict__ bg,
    const float* __restrict__ Wo, const float* __restrict__ bo,
    const uint4* __restrict__ wsf, float* __restrict__ out)
{
  __shared__ u16 sZ [256][LDZ];       // zn[pos][ch] bf16                  20480 B
  __shared__ u16 sK [2][128][LDK];    // K[key%128][ch]  (double-buffered) 18432 B
  __shared__ u16 sVt[2][32][LDV];     // V^T[ch][key%128](double-buffered) 16896 B

  const int qhalf = blockIdx.x;
  const int i     = blockIdx.y;
  const int tid   = threadIdx.x;
  const int wave  = tid >> 6, lane = tid & 63, quad = lane >> 4, col = lane & 15;
  const f32x4 z4  = {0.f, 0.f, 0.f, 0.f};

  // ---------------- phase 0: LayerNorm (one thread per position) ----------------
  {
    const float* zr = z + (((i << 8) + tid) << 5);
    float x[32];
#pragma unroll
    for (int e = 0; e < 8; e++) {
      const float4 v = *(const float4*)(zr + e*4);
      x[4*e] = v.x; x[4*e+1] = v.y; x[4*e+2] = v.z; x[4*e+3] = v.w;
    }
    float mu = 0.f;
#pragma unroll
    for (int c = 0; c < 32; c++) mu += x[c];
    mu *= (1.f / 32.f);
    float s2 = 0.f;
#pragma unroll
    for (int c = 0; c < 32; c++) { float d = x[c] - mu; s2 += d * d; }
    const float rstd = __builtin_amdgcn_rsqf(s2 * (1.f / 32.f) + 1e-5f);
    u32* dst = (u32*)&sZ[tid][0];
#pragma unroll
    for (int e = 0; e < 16; e++) {
      const float za = (x[2*e]   - mu) * rstd * ln_g[2*e]   + ln_b[2*e];
      const float zb = (x[2*e+1] - mu) * rstd * ln_g[2*e+1] + ln_b[2*e+1];
      dst[e] = pk(za, zb);
    }
  }
  __syncthreads();

  f32x4 acc[2][2] = {{z4, z4}, {z4, z4}};   // fp32 out accumulators (across heads)
  const float k2e = 0.17677669529663687f * 1.44269504089f;   // (1/sqrt32)*log2(e)

  // all-ones bf16 A-fragment for the l-reduction MFMA
  U8 ONESF;
#pragma unroll
  for (int j = 0; j < 4; j++) ONESF.u[j] = 0x3F803F80u;   // bf16 1.0 pairs

  // weight fragment loader: prepacked 16B load (PP) or f32 load + pack
  auto ldw = [&](int mat, int h, int cb) -> U8 {
    U8 t;
    if constexpr (PP) {
      *(uint4*)t.u = wsf[(mat*8 + h*2 + cb)*64 + lane];
    } else {
      const float* W = (mat==0) ? Wq : (mat==1) ? Wk : (mat==2) ? Wv : Wg;
      const float* p = W + h*1024 + (cb*16 + col)*32 + quad*8;
      const float4 a = *(const float4*)(p);
      const float4 b = *(const float4*)(p + 4);
      t.u[0] = pk(a.x, a.y); t.u[1] = pk(a.z, a.w);
      t.u[2] = pk(b.x, b.y); t.u[3] = pk(b.z, b.w);
    }
    return t;
  };

  U8    QB[2];       // Q (pre-scaled) permuted-k B-frags, per head
  float G[2][8];     // gates, O^T C-layout, per head

  // Q/G for head h: this block's 128 queries (2 tiles/wave); reads sZ only
  auto qg = [&](int h) {
    const U8 WqF0 = ldw(0,h,0), WqF1 = ldw(0,h,1);
    const U8 WgF0 = ldw(3,h,0), WgF1 = ldw(3,h,1);
    float bgl[8];
#pragma unroll
    for (int r = 0; r < 4; r++) {
      bgl[r]     = bg[h*32 + quad*4 + r];
      bgl[4 + r] = bg[h*32 + 16 + quad*4 + r];
    }
#pragma unroll
    for (int p2 = 0; p2 < 2; p2++) {
      const int row = qhalf*128 + (p2*4 + wave)*16 + col;
      U8 ZA;
      {
        const uint4 v = *(const uint4*)&sZ[row][quad*8];
        ZA.u[0] = v.x; ZA.u[1] = v.y; ZA.u[2] = v.z; ZA.u[3] = v.w;
      }
      const f32x4 q0 = mfma16(WqF0.b, ZA.b, z4);
      const f32x4 q1 = mfma16(WqF1.b, ZA.b, z4);
      const f32x4 g0 = mfma16(WgF0.b, ZA.b, z4);
      const f32x4 g1 = mfma16(WgF1.b, ZA.b, z4);
      if constexpr (PP) {   // scale already folded into Wq by prepack
        QB[p2].u[0] = pk(q0[0], q0[1]); QB[p2].u[1] = pk(q0[2], q0[3]);
        QB[p2].u[2] = pk(q1[0], q1[1]); QB[p2].u[3] = pk(q1[2], q1[3]);
      } else {
        QB[p2].u[0] = pk(q0[0]*k2e, q0[1]*k2e); QB[p2].u[1] = pk(q0[2]*k2e, q0[3]*k2e);
        QB[p2].u[2] = pk(q1[0]*k2e, q1[1]*k2e); QB[p2].u[3] = pk(q1[2]*k2e, q1[3]*k2e);
      }
#pragma unroll
      for (int r = 0; r < 4; r++) {
        G[p2][r]     = sigm(g0[r] + bgl[r]);
        G[p2][4 + r] = sigm(g1[r] + bgl[4 + r]);
      }
    }
  };

  // project keys m*128..m*128+127 into buffer buf (reads sZ only)
  auto proj = [&](const U8& K0w, const U8& K1w, const U8& V0w, const U8& V1w,
                  int m, int buf) {
#pragma unroll
    for (int pp = 0; pp < 2; pp++) {
      const int lbase = (pp*4 + wave) * 16;        // local key base (0..112)
      const int grow  = m*128 + lbase + col;       // global position
      U8 ZA;
      {
        const uint4 v = *(const uint4*)&sZ[grow][quad*8];
        ZA.u[0] = v.x; ZA.u[1] = v.y; ZA.u[2] = v.z; ZA.u[3] = v.w;
      }
      // K^T (C-layout: ch=quad*4+reg, key=col), V (key=quad*4+reg, ch=col)
      const f32x4 k0 = mfma16(K0w.b, ZA.b, z4);
      const f32x4 k1 = mfma16(K1w.b, ZA.b, z4);
      const f32x4 v0 = mfma16(ZA.b, V0w.b, z4);
      const f32x4 v1 = mfma16(ZA.b, V1w.b, z4);
      *(uint2*)&sK[buf][lbase + col][quad*4]        = make_uint2(pk(k0[0],k0[1]), pk(k0[2],k0[3]));
      *(uint2*)&sK[buf][lbase + col][16 + quad*4]   = make_uint2(pk(k1[0],k1[1]), pk(k1[2],k1[3]));
      *(uint2*)&sVt[buf][col][lbase + quad*4]       = make_uint2(pk(v0[0],v0[1]), pk(v0[2],v0[3]));
      *(uint2*)&sVt[buf][16 + col][lbase + quad*4]  = make_uint2(pk(v1[0],v1[1]), pk(v1[2],v1[3]));
    }
  };

  // -------- prologue: head 0 Q/G + first half projection --------
  U8 KC0 = ldw(1,0,0), KC1 = ldw(1,0,1);   // current head's K/V weight frags
  U8 VC0 = ldw(2,0,0), VC1 = ldw(2,0,1);
  qg(0);
  proj(KC0, KC1, VC0, VC1, 0, 0);
  __syncthreads();

  for (int h = 0; h < 4; ++h) {
    f32x4 lacc[2] = {z4, z4};               // l via ONES-MFMA: rows identical
    f32x4 O[2][2] = {{z4, z4}, {z4, z4}};   // O^T per p2: ch=quad*4+r (+16), q=col

    // attention over one buffered half: 2-slot software pipeline — issue
    // kb+1's 8 ds_reads before computing kb (slot idx kb&1 is compile-time
    // constant after full unroll; loads fly under the S->exp2->pack->PV tail)
    auto attend = [&](int buf) {
#pragma unroll
      for (int p2 = 0; p2 < 2; p2++) {
        U8 KF0[2], KF1[2], VF0[2], VF1[2];
        auto loadf = [&](int kbi, int slot) {
          const int kb = kbi * 32;
          const uint2 a = *(const uint2*)&sK[buf][kb + col][quad*4];
          const uint2 b = *(const uint2*)&sK[buf][kb + col][16 + quad*4];
          KF0[slot].u[0] = a.x; KF0[slot].u[1] = a.y;
          KF0[slot].u[2] = b.x; KF0[slot].u[3] = b.y;
          const uint2 c = *(const uint2*)&sK[buf][kb + 16 + col][quad*4];
          const uint2 d = *(const uint2*)&sK[buf][kb + 16 + col][16 + quad*4];
          KF1[slot].u[0] = c.x; KF1[slot].u[1] = c.y;
          KF1[slot].u[2] = d.x; KF1[slot].u[3] = d.y;
          const uint2 e = *(const uint2*)&sVt[buf][col][kb + quad*4];
          const uint2 f = *(const uint2*)&sVt[buf][col][kb + 16 + quad*4];
          VF0[slot].u[0] = e.x; VF0[slot].u[1] = e.y;
          VF0[slot].u[2] = f.x; VF0[slot].u[3] = f.y;
          const uint2 g = *(const uint2*)&sVt[buf][16 + col][kb + quad*4];
          const uint2 k = *(const uint2*)&sVt[buf][16 + col][kb + 16 + quad*4];
          VF1[slot].u[0] = g.x; VF1[slot].u[1] = g.y;
          VF1[slot].u[2] = k.x; VF1[slot].u[3] = k.y;
        };
        loadf(0, 0);                       // prologue
#pragma unroll
        for (int kbi = 0; kbi < 4; kbi++) {
          const int cur = kbi & 1;
          if (kbi < 3) loadf(kbi + 1, cur ^ 1);   // prefetch next tile
          const f32x4 S0 = mfma16(KF0[cur].b, QB[p2].b, z4);   // keys kb+quad*4+r
          const f32x4 S1 = mfma16(KF1[cur].b, QB[p2].b, z4);   // keys kb+16+quad*4+r
          float ps[8];
#pragma unroll
          for (int r = 0; r < 4; r++) {
            ps[r]     = ex2(S0[r]);     // scale pre-folded into Q; raw v_exp_f32
            ps[4 + r] = ex2(S1[r]);
          }
          U8 PB;
          PB.u[0] = pk(ps[0],ps[1]); PB.u[1] = pk(ps[2],ps[3]);
          PB.u[2] = pk(ps[4],ps[5]); PB.u[3] = pk(ps[6],ps[7]);
          // l on the MFMA pipe: every row of lacc = sum over these 32 keys
          lacc[p2] = mfma16(ONESF.b, PB.b, lacc[p2]);
          O[p2][0] = mfma16(VF0[cur].b, PB.b, O[p2][0]);
          O[p2][1] = mfma16(VF1[cur].b, PB.b, O[p2][1]);
        }
      }
    };

    // ---- stage A: proj(head h, half 1 -> buf1) overlapped with attend(buf0) ----
    proj(KC0, KC1, VC0, VC1, 1, 1);
    attend(0);
    __syncthreads();   // buf1 ready; buf0 free

    // ---- stage B: proj(head h+1, half 0 -> buf0) overlapped with attend(buf1) ----
    if (h < 3) {
      const U8 KN0 = ldw(1,h+1,0), KN1 = ldw(1,h+1,1);
      const U8 VN0 = ldw(2,h+1,0), VN1 = ldw(2,h+1,1);
      proj(KN0, KN1, VN0, VN1, 0, 0);
      KC0 = KN0; KC1 = KN1; VC0 = VN0; VC1 = VN1;
    }
    attend(1);
    __syncthreads();   // buf0 ready for next head; buf1 free

    // -------- epilogue: normalize, gate, fused out-projection (regs only) --------
    U8 WoA0, WoA1;   // Wo A-frags with matching k-permutation (qt-invariant)
    if constexpr (PP) {
      *(uint4*)WoA0.u = wsf[(32 + h*2 + 0)*64 + lane];
      *(uint4*)WoA1.u = wsf[(32 + h*2 + 1)*64 + lane];
    } else {
      const float4 a = *(const float4*)(Wo + col*128 + h*32 + quad*4);
      const float4 b = *(const float4*)(Wo + col*128 + h*32 + 16 + quad*4);
      WoA0.u[0] = pk(a.x,a.y); WoA0.u[1] = pk(a.z,a.w);
      WoA0.u[2] = pk(b.x,b.y); WoA0.u[3] = pk(b.z,b.w);
      const float4 c = *(const float4*)(Wo + (16 + col)*128 + h*32 + quad*4);
      const float4 d = *(const float4*)(Wo + (16 + col)*128 + h*32 + 16 + quad*4);
      WoA1.u[0] = pk(c.x,c.y); WoA1.u[1] = pk(c.z,c.w);
      WoA1.u[2] = pk(d.x,d.y); WoA1.u[3] = pk(d.z,d.w);
    }
#pragma unroll
    for (int p2 = 0; p2 < 2; p2++) {
      const float inv = __builtin_amdgcn_rcpf(lacc[p2][0]);   // full 256-key sum
      float og[8];
#pragma unroll
      for (int r = 0; r < 4; r++) {
        og[r]     = O[p2][0][r] * inv * G[p2][r];
        og[4 + r] = O[p2][1][r] * inv * G[p2][4 + r];
      }
      U8 OB;   // gated O^T as permuted-k B-frag (k-permutation matches WoA)
      OB.u[0] = pk(og[0],og[1]); OB.u[1] = pk(og[2],og[3]);
      OB.u[2] = pk(og[4],og[5]); OB.u[3] = pk(og[6],og[7]);
      acc[p2][0] = mfma16(WoA0.b, OB.b, acc[p2][0]);   // couts 0..15
      acc[p2][1] = mfma16(WoA1.b, OB.b, acc[p2][1]);   // couts 16..31
    }

    if (h < 3) qg(h + 1);   // Q/G for next head (reads sZ only; after epilogue
                            // so G of head h is consumed before overwrite)
  }

  // ---------------- epilogue: + bo, float4 stores ----------------
  float bo0[4], bo1[4];
#pragma unroll
  for (int r = 0; r < 4; r++) {
    bo0[r] = bo[quad*4 + r];
    bo1[r] = bo[16 + quad*4 + r];
  }
#pragma unroll
  for (int p2 = 0; p2 < 2; p2++) {
    const int pos = (i << 8) + qhalf*128 + (p2*4 + wave)*16 + col;
    float* op = out + pos*32;
    *(float4*)(op + quad*4)      = make_float4(acc[p2][0][0] + bo0[0], acc[p2][0][1] + bo0[1],
                                               acc[p2][0][2] + bo0[2], acc[p2][0][3] + bo0[3]);
    *(float4*)(op + 16 + quad*4) = make_float4(acc[p2][1][0] + bo1[0], acc[p2][1][1] + bo1[1],
                                               acc[p2][1][2] + bo1[2], acc[p2][1][3] + bo1[3]);
  }
}

extern "C" void kernel_launch(void* const* d_in, const int* in_sizes, int n_in,
                              void* d_out, int out_size, void* d_ws, size_t ws_size,
                              hipStream_t stream)
{
  const float* z    = (const float*)d_in[0];
  const float* ln_g = (const float*)d_in[1];
  const float* ln_b = (const float*)d_in[2];
  const float* Wq   = (const float*)d_in[3];
  const float* Wk   = (const float*)d_in[4];
  const float* Wv   = (const float*)d_in[5];
  // d_in[6] = Wb: softmax shift invariance -> exactly cancels, unused.
  const float* Wg   = (const float*)d_in[7];
  const float* bg   = (const float*)d_in[8];
  const float* Wo   = (const float*)d_in[9];
  const float* bo   = (const float*)d_in[10];

  if (ws_size >= 40960) {
    prepack_w<<<dim3(10), 256, 0, stream>>>(Wq, Wk, Wv, Wg, Wo, (uint4*)d_ws);
    tri_attn_fused<true><<<dim3(2, 256), 256, 0, stream>>>(
        z, ln_g, ln_b, Wq, Wk, Wv, Wg, bg, Wo, bo, (const uint4*)d_ws, (float*)d_out);
  } else {
    tri_attn_fused<false><<<dim3(2, 256), 256, 0, stream>>>(
        z, ln_g, ln_b, Wq, Wk, Wv, Wg, bg, Wo, bo, (const uint4*)d_ws, (float*)d_out);
  }
}

// Round 15
// 105.091 us; speedup vs baseline: 1.0784x; 1.0031x over previous
//
#include <hip/hip_runtime.h>

// TriangleAttentionStartingNode — MI355X gfx950. f32 global I/O, bf16 MFMA compute.
//
// R19: setprio round (T5 — last untried catalog technique for this
// structure). R18's attend-prefetch was FLAT -> ds_reads already hidden;
// residual = S-MFMA -> exp2 -> pack -> PV chain x512 iters at 2 waves/SIMD.
// Not a HW roofline (14.5 GFLOP -> ~7us MFMA-bound; 17MB -> ~3us BW-bound;
// we're at ~36.5us, MfmaUtil ~11%) — structural latency floor. T5 mechanism
// fits: 8 waves/CU at DIFFERENT phase points (barriers only 2x/head);
// s_setprio(1) around a wave's MFMA clusters lets its matrix ops preempt
// other waves' LDS/TRANS issue, compressing the exposed chain tail via
// cross-wave arbitration (catalog: attn +4-7%, m191). One variable vs R18:
// setprio brackets on attend's S-pair and lacc/PV clusters (4 SALU/iter,
// co-issued). Prediction: −1.5-3us if arbitration slack exists; if flat,
// structure is at its practical floor and next round declares it.
//
// Kept from R18: 2-slot attend prefetch (flat but harmless). From R17:
// weight prepack (40KB d_ws, Wq pre-scaled; −6us). From R16: l via
// ONES-MFMA. From R14: double-buffered sK/sVt + {proj||attend} pipeline.
// From R12: raw HW transcendentals (−9us). Grid (2,256), 256 thr; plain
// __launch_bounds__(256); v_perm round-half-up pack (R15 cvt_pk corrupts);
// Wb unused (softmax shift invariance).

typedef unsigned short u16;
typedef unsigned int   u32;
typedef __bf16 bf16x8 __attribute__((ext_vector_type(8)));
typedef float  f32x4  __attribute__((ext_vector_type(4)));

union U8 { bf16x8 b; u32 u[4]; };

// round-half-up f32->bf16 pair pack: 2 adds + 1 v_perm (proven)
__device__ __forceinline__ u32 pk(float a, float b) {
  const u32 au = __float_as_uint(a) + 0x8000u;
  const u32 bu = __float_as_uint(b) + 0x8000u;
  return __builtin_amdgcn_perm(bu, au, 0x07060302u);  // {b.hi16, a.hi16}
}
__device__ __forceinline__ f32x4 mfma16(bf16x8 a, bf16x8 b, f32x4 c) {
  return __builtin_amdgcn_mfma_f32_16x16x32_bf16(a, b, c, 0, 0, 0);
}
// raw v_exp_f32 (no libm denormal fixup)
__device__ __forceinline__ float ex2(float x) { return __builtin_amdgcn_exp2f(x); }
// sigmoid via v_exp + v_rcp (1 ulp)
__device__ __forceinline__ float sigm(float x) {
  return __builtin_amdgcn_rcpf(1.f + __builtin_amdgcn_exp2f(-1.44269504089f * x));
}

#define LDZ 40    // 80 B rows (16B-aligned uint4 reads)
#define LDK 36    // 72 B rows
#define LDV 132   // 264 B rows

// ---------------- prepack: all weight fragments -> bf16 in d_ws ----------------
// ws layout (uint4 units): [mat 0..3][h 0..3][cb 0..1][lane] at
// (mat*8 + h*2 + cb)*64 + lane; Wo at (32 + h*2 + half)*64 + lane.
// 40 groups x 64 lanes x 16B = 40960 B.
__global__ __launch_bounds__(256) void prepack_w(
    const float* __restrict__ Wq, const float* __restrict__ Wk,
    const float* __restrict__ Wv, const float* __restrict__ Wg,
    const float* __restrict__ Wo, uint4* __restrict__ ws)
{
  const int t    = blockIdx.x * 256 + threadIdx.x;    // 0..2559
  const int lane = t & 63;
  const int quad = lane >> 4, col = lane & 15;
  const int fid  = t >> 6;                            // 0..39
  const float k2e = 0.17677669529663687f * 1.44269504089f;
  U8 f;
  if (fid < 32) {
    const int mat = fid >> 3, h = (fid >> 1) & 3, cb = fid & 1;
    const float* W = (mat == 0) ? Wq : (mat == 1) ? Wk : (mat == 2) ? Wv : Wg;
    const float s  = (mat == 0) ? k2e : 1.f;          // softmax scale folded into Wq
    const float* p = W + h*1024 + (cb*16 + col)*32 + quad*8;
    const float4 a = *(const float4*)(p);
    const float4 b = *(const float4*)(p + 4);
    f.u[0] = pk(a.x*s, a.y*s); f.u[1] = pk(a.z*s, a.w*s);
    f.u[2] = pk(b.x*s, b.y*s); f.u[3] = pk(b.z*s, b.w*s);
  } else {
    const int g = fid - 32, h = g >> 1, hf = g & 1;
    const float* p = Wo + (hf*16 + col)*128 + h*32 + quad*4;
    const float4 a = *(const float4*)(p);
    const float4 b = *(const float4*)(p + 16);
    f.u[0] = pk(a.x,a.y); f.u[1] = pk(a.z,a.w);
    f.u[2] = pk(b.x,b.y); f.u[3] = pk(b.z,b.w);
  }
  ws[fid*64 + lane] = *(const uint4*)f.u;
}

template <bool PP>
__global__ __launch_bounds__(256) void tri_attn_fused(
    const float* __restrict__ z,  const float* __restrict__ ln_g, const float* __restrict__ ln_b,
    const float* __restrict__ Wq, const float* __restrict__ Wk,   const float* __restrict__ Wv,
    const float* __restrict__ Wg, const float* __restrict__ bg,
    const float* __restrict__ Wo, const float* __restrict__ bo,
    const uint4* __restrict__ wsf, float* __restrict__ out)
{
  __shared__ u16 sZ [256][LDZ];       // zn[pos][ch] bf16                  20480 B
  __shared__ u16 sK [2][128][LDK];    // K[key%128][ch]  (double-buffered) 18432 B
  __shared__ u16 sVt[2][32][LDV];     // V^T[ch][key%128](double-buffered) 16896 B

  const int qhalf = blockIdx.x;
  const int i     = blockIdx.y;
  const int tid   = threadIdx.x;
  const int wave  = tid >> 6, lane = tid & 63, quad = lane >> 4, col = lane & 15;
  const f32x4 z4  = {0.f, 0.f, 0.f, 0.f};

  // ---------------- phase 0: LayerNorm (one thread per position) ----------------
  {
    const float* zr = z + (((i << 8) + tid) << 5);
    float x[32];
#pragma unroll
    for (int e = 0; e < 8; e++) {
      const float4 v = *(const float4*)(zr + e*4);
      x[4*e] = v.x; x[4*e+1] = v.y; x[4*e+2] = v.z; x[4*e+3] = v.w;
    }
    float mu = 0.f;
#pragma unroll
    for (int c = 0; c < 32; c++) mu += x[c];
    mu *= (1.f / 32.f);
    float s2 = 0.f;
#pragma unroll
    for (int c = 0; c < 32; c++) { float d = x[c] - mu; s2 += d * d; }
    const float rstd = __builtin_amdgcn_rsqf(s2 * (1.f / 32.f) + 1e-5f);
    u32* dst = (u32*)&sZ[tid][0];
#pragma unroll
    for (int e = 0; e < 16; e++) {
      const float za = (x[2*e]   - mu) * rstd * ln_g[2*e]   + ln_b[2*e];
      const float zb = (x[2*e+1] - mu) * rstd * ln_g[2*e+1] + ln_b[2*e+1];
      dst[e] = pk(za, zb);
    }
  }
  __syncthreads();

  f32x4 acc[2][2] = {{z4, z4}, {z4, z4}};   // fp32 out accumulators (across heads)
  const float k2e = 0.17677669529663687f * 1.44269504089f;   // (1/sqrt32)*log2(e)

  // all-ones bf16 A-fragment for the l-reduction MFMA
  U8 ONESF;
#pragma unroll
  for (int j = 0; j < 4; j++) ONESF.u[j] = 0x3F803F80u;   // bf16 1.0 pairs

  // weight fragment loader: prepacked 16B load (PP) or f32 load + pack
  auto ldw = [&](int mat, int h, int cb) -> U8 {
    U8 t;
    if constexpr (PP) {
      *(uint4*)t.u = wsf[(mat*8 + h*2 + cb)*64 + lane];
    } else {
      const float* W = (mat==0) ? Wq : (mat==1) ? Wk : (mat==2) ? Wv : Wg;
      const float* p = W + h*1024 + (cb*16 + col)*32 + quad*8;
      const float4 a = *(const float4*)(p);
      const float4 b = *(const float4*)(p + 4);
      t.u[0] = pk(a.x, a.y); t.u[1] = pk(a.z, a.w);
      t.u[2] = pk(b.x, b.y); t.u[3] = pk(b.z, b.w);
    }
    return t;
  };

  U8    QB[2];       // Q (pre-scaled) permuted-k B-frags, per head
  float G[2][8];     // gates, O^T C-layout, per head

  // Q/G for head h: this block's 128 queries (2 tiles/wave); reads sZ only
  auto qg = [&](int h) {
    const U8 WqF0 = ldw(0,h,0), WqF1 = ldw(0,h,1);
    const U8 WgF0 = ldw(3,h,0), WgF1 = ldw(3,h,1);
    float bgl[8];
#pragma unroll
    for (int r = 0; r < 4; r++) {
      bgl[r]     = bg[h*32 + quad*4 + r];
      bgl[4 + r] = bg[h*32 + 16 + quad*4 + r];
    }
#pragma unroll
    for (int p2 = 0; p2 < 2; p2++) {
      const int row = qhalf*128 + (p2*4 + wave)*16 + col;
      U8 ZA;
      {
        const uint4 v = *(const uint4*)&sZ[row][quad*8];
        ZA.u[0] = v.x; ZA.u[1] = v.y; ZA.u[2] = v.z; ZA.u[3] = v.w;
      }
      const f32x4 q0 = mfma16(WqF0.b, ZA.b, z4);
      const f32x4 q1 = mfma16(WqF1.b, ZA.b, z4);
      const f32x4 g0 = mfma16(WgF0.b, ZA.b, z4);
      const f32x4 g1 = mfma16(WgF1.b, ZA.b, z4);
      if constexpr (PP) {   // scale already folded into Wq by prepack
        QB[p2].u[0] = pk(q0[0], q0[1]); QB[p2].u[1] = pk(q0[2], q0[3]);
        QB[p2].u[2] = pk(q1[0], q1[1]); QB[p2].u[3] = pk(q1[2], q1[3]);
      } else {
        QB[p2].u[0] = pk(q0[0]*k2e, q0[1]*k2e); QB[p2].u[1] = pk(q0[2]*k2e, q0[3]*k2e);
        QB[p2].u[2] = pk(q1[0]*k2e, q1[1]*k2e); QB[p2].u[3] = pk(q1[2]*k2e, q1[3]*k2e);
      }
#pragma unroll
      for (int r = 0; r < 4; r++) {
        G[p2][r]     = sigm(g0[r] + bgl[r]);
        G[p2][4 + r] = sigm(g1[r] + bgl[4 + r]);
      }
    }
  };

  // project keys m*128..m*128+127 into buffer buf (reads sZ only)
  auto proj = [&](const U8& K0w, const U8& K1w, const U8& V0w, const U8& V1w,
                  int m, int buf) {
#pragma unroll
    for (int pp = 0; pp < 2; pp++) {
      const int lbase = (pp*4 + wave) * 16;        // local key base (0..112)
      const int grow  = m*128 + lbase + col;       // global position
      U8 ZA;
      {
        const uint4 v = *(const uint4*)&sZ[grow][quad*8];
        ZA.u[0] = v.x; ZA.u[1] = v.y; ZA.u[2] = v.z; ZA.u[3] = v.w;
      }
      // K^T (C-layout: ch=quad*4+reg, key=col), V (key=quad*4+reg, ch=col)
      const f32x4 k0 = mfma16(K0w.b, ZA.b, z4);
      const f32x4 k1 = mfma16(K1w.b, ZA.b, z4);
      const f32x4 v0 = mfma16(ZA.b, V0w.b, z4);
      const f32x4 v1 = mfma16(ZA.b, V1w.b, z4);
      *(uint2*)&sK[buf][lbase + col][quad*4]        = make_uint2(pk(k0[0],k0[1]), pk(k0[2],k0[3]));
      *(uint2*)&sK[buf][lbase + col][16 + quad*4]   = make_uint2(pk(k1[0],k1[1]), pk(k1[2],k1[3]));
      *(uint2*)&sVt[buf][col][lbase + quad*4]       = make_uint2(pk(v0[0],v0[1]), pk(v0[2],v0[3]));
      *(uint2*)&sVt[buf][16 + col][lbase + quad*4]  = make_uint2(pk(v1[0],v1[1]), pk(v1[2],v1[3]));
    }
  };

  // -------- prologue: head 0 Q/G + first half projection --------
  U8 KC0 = ldw(1,0,0), KC1 = ldw(1,0,1);   // current head's K/V weight frags
  U8 VC0 = ldw(2,0,0), VC1 = ldw(2,0,1);
  qg(0);
  proj(KC0, KC1, VC0, VC1, 0, 0);
  __syncthreads();

  for (int h = 0; h < 4; ++h) {
    f32x4 lacc[2] = {z4, z4};               // l via ONES-MFMA: rows identical
    f32x4 O[2][2] = {{z4, z4}, {z4, z4}};   // O^T per p2: ch=quad*4+r (+16), q=col

    // attention over one buffered half: 2-slot prefetch pipeline + T5
    // setprio brackets on the MFMA clusters (cross-wave arbitration)
    auto attend = [&](int buf) {
#pragma unroll
      for (int p2 = 0; p2 < 2; p2++) {
        U8 KF0[2], KF1[2], VF0[2], VF1[2];
        auto loadf = [&](int kbi, int slot) {
          const int kb = kbi * 32;
          const uint2 a = *(const uint2*)&sK[buf][kb + col][quad*4];
          const uint2 b = *(const uint2*)&sK[buf][kb + col][16 + quad*4];
          KF0[slot].u[0] = a.x; KF0[slot].u[1] = a.y;
          KF0[slot].u[2] = b.x; KF0[slot].u[3] = b.y;
          const uint2 c = *(const uint2*)&sK[buf][kb + 16 + col][quad*4];
          const uint2 d = *(const uint2*)&sK[buf][kb + 16 + col][16 + quad*4];
          KF1[slot].u[0] = c.x; KF1[slot].u[1] = c.y;
          KF1[slot].u[2] = d.x; KF1[slot].u[3] = d.y;
          const uint2 e = *(const uint2*)&sVt[buf][col][kb + quad*4];
          const uint2 f = *(const uint2*)&sVt[buf][col][kb + 16 + quad*4];
          VF0[slot].u[0] = e.x; VF0[slot].u[1] = e.y;
          VF0[slot].u[2] = f.x; VF0[slot].u[3] = f.y;
          const uint2 g = *(const uint2*)&sVt[buf][16 + col][kb + quad*4];
          const uint2 k = *(const uint2*)&sVt[buf][16 + col][kb + 16 + quad*4];
          VF1[slot].u[0] = g.x; VF1[slot].u[1] = g.y;
          VF1[slot].u[2] = k.x; VF1[slot].u[3] = k.y;
        };
        loadf(0, 0);                       // prologue
#pragma unroll
        for (int kbi = 0; kbi < 4; kbi++) {
          const int cur = kbi & 1;
          if (kbi < 3) loadf(kbi + 1, cur ^ 1);   // prefetch next tile
          __builtin_amdgcn_s_setprio(1);
          const f32x4 S0 = mfma16(KF0[cur].b, QB[p2].b, z4);   // keys kb+quad*4+r
          const f32x4 S1 = mfma16(KF1[cur].b, QB[p2].b, z4);   // keys kb+16+quad*4+r
          __builtin_amdgcn_s_setprio(0);
          float ps[8];
#pragma unroll
          for (int r = 0; r < 4; r++) {
            ps[r]     = ex2(S0[r]);     // scale pre-folded into Q; raw v_exp_f32
            ps[4 + r] = ex2(S1[r]);
          }
          U8 PB;
          PB.u[0] = pk(ps[0],ps[1]); PB.u[1] = pk(ps[2],ps[3]);
          PB.u[2] = pk(ps[4],ps[5]); PB.u[3] = pk(ps[6],ps[7]);
          __builtin_amdgcn_s_setprio(1);
          // l on the MFMA pipe: every row of lacc = sum over these 32 keys
          lacc[p2] = mfma16(ONESF.b, PB.b, lacc[p2]);
          O[p2][0] = mfma16(VF0[cur].b, PB.b, O[p2][0]);
          O[p2][1] = mfma16(VF1[cur].b, PB.b, O[p2][1]);
          __builtin_amdgcn_s_setprio(0);
        }
      }
    };

    // ---- stage A: proj(head h, half 1 -> buf1) overlapped with attend(buf0) ----
    proj(KC0, KC1, VC0, VC1, 1, 1);
    attend(0);
    __syncthreads();   // buf1 ready; buf0 free

    // ---- stage B: proj(head h+1, half 0 -> buf0) overlapped with attend(buf1) ----
    if (h < 3) {
      const U8 KN0 = ldw(1,h+1,0), KN1 = ldw(1,h+1,1);
      const U8 VN0 = ldw(2,h+1,0), VN1 = ldw(2,h+1,1);
      proj(KN0, KN1, VN0, VN1, 0, 0);
      KC0 = KN0; KC1 = KN1; VC0 = VN0; VC1 = VN1;
    }
    attend(1);
    __syncthreads();   // buf0 ready for next head; buf1 free

    // -------- epilogue: normalize, gate, fused out-projection (regs only) --------
    U8 WoA0, WoA1;   // Wo A-frags with matching k-permutation (qt-invariant)
    if constexpr (PP) {
      *(uint4*)WoA0.u = wsf[(32 + h*2 + 0)*64 + lane];
      *(uint4*)WoA1.u = wsf[(32 + h*2 + 1)*64 + lane];
    } else {
      const float4 a = *(const float4*)(Wo + col*128 + h*32 + quad*4);
      const float4 b = *(const float4*)(Wo + col*128 + h*32 + 16 + quad*4);
      WoA0.u[0] = pk(a.x,a.y); WoA0.u[1] = pk(a.z,a.w);
      WoA0.u[2] = pk(b.x,b.y); WoA0.u[3] = pk(b.z,b.w);
      const float4 c = *(const float4*)(Wo + (16 + col)*128 + h*32 + quad*4);
      const float4 d = *(const float4*)(Wo + (16 + col)*128 + h*32 + 16 + quad*4);
      WoA1.u[0] = pk(c.x,c.y); WoA1.u[1] = pk(c.z,c.w);
      WoA1.u[2] = pk(d.x,d.y); WoA1.u[3] = pk(d.z,d.w);
    }
#pragma unroll
    for (int p2 = 0; p2 < 2; p2++) {
      const float inv = __builtin_amdgcn_rcpf(lacc[p2][0]);   // full 256-key sum
      float og[8];
#pragma unroll
      for (int r = 0; r < 4; r++) {
        og[r]     = O[p2][0][r] * inv * G[p2][r];
        og[4 + r] = O[p2][1][r] * inv * G[p2][4 + r];
      }
      U8 OB;   // gated O^T as permuted-k B-frag (k-permutation matches WoA)
      OB.u[0] = pk(og[0],og[1]); OB.u[1] = pk(og[2],og[3]);
      OB.u[2] = pk(og[4],og[5]); OB.u[3] = pk(og[6],og[7]);
      acc[p2][0] = mfma16(WoA0.b, OB.b, acc[p2][0]);   // couts 0..15
      acc[p2][1] = mfma16(WoA1.b, OB.b, acc[p2][1]);   // couts 16..31
    }

    if (h < 3) qg(h + 1);   // Q/G for next head (reads sZ only; after epilogue
                            // so G of head h is consumed before overwrite)
  }

  // ---------------- epilogue: + bo, float4 stores ----------------
  float bo0[4], bo1[4];
#pragma unroll
  for (int r = 0; r < 4; r++) {
    bo0[r] = bo[quad*4 + r];
    bo1[r] = bo[16 + quad*4 + r];
  }
#pragma unroll
  for (int p2 = 0; p2 < 2; p2++) {
    const int pos = (i << 8) + qhalf*128 + (p2*4 + wave)*16 + col;
    float* op = out + pos*32;
    *(float4*)(op + quad*4)      = make_float4(acc[p2][0][0] + bo0[0], acc[p2][0][1] + bo0[1],
                                               acc[p2][0][2] + bo0[2], acc[p2][0][3] + bo0[3]);
    *(float4*)(op + 16 + quad*4) = make_float4(acc[p2][1][0] + bo1[0], acc[p2][1][1] + bo1[1],
                                               acc[p2][1][2] + bo1[2], acc[p2][1][3] + bo1[3]);
  }
}

extern "C" void kernel_launch(void* const* d_in, const int* in_sizes, int n_in,
                              void* d_out, int out_size, void* d_ws, size_t ws_size,
                              hipStream_t stream)
{
  const float* z    = (const float*)d_in[0];
  const float* ln_g = (const float*)d_in[1];
  const float* ln_b = (const float*)d_in[2];
  const float* Wq   = (const float*)d_in[3];
  const float* Wk   = (const float*)d_in[4];
  const float* Wv   = (const float*)d_in[5];
  // d_in[6] = Wb: softmax shift invariance -> exactly cancels, unused.
  const float* Wg   = (const float*)d_in[7];
  const float* bg   = (const float*)d_in[8];
  const float* Wo   = (const float*)d_in[9];
  const float* bo   = (const float*)d_in[10];

  if (ws_size >= 40960) {
    prepack_w<<<dim3(10), 256, 0, stream>>>(Wq, Wk, Wv, Wg, Wo, (uint4*)d_ws);
    tri_attn_fused<true><<<dim3(2, 256), 256, 0, stream>>>(
        z, ln_g, ln_b, Wq, Wk, Wv, Wg, bg, Wo, bo, (const uint4*)d_ws, (float*)d_out);
  } else {
    tri_attn_fused<false><<<dim3(2, 256), 256, 0, stream>>>(
        z, ln_g, ln_b, Wq, Wk, Wv, Wg, bg, Wo, bo, (const uint4*)d_ws, (float*)d_out);
  }
}